// Round 1
// baseline (1068.522 us; speedup 1.0000x reference)
//
#include <hip/hip_runtime.h>
#include <cstdint>
#include <cstddef>

#define N_NODES 100000
#define N_EDGES 1600000

// ---------------------------------------------------------------------------
// edge_index dtype handling: JAX requests int64 but (with x64 disabled) may
// deliver int32. Detect on-device: for int64, the high 32-bit word of every
// element is 0 (values in [0,1e5)); for int32, odd words are random values.
// ---------------------------------------------------------------------------
static __device__ __forceinline__ int edge_row(const void* ei, int i64, int e) {
    return i64 ? (int)((const long long*)ei)[e] : ((const int*)ei)[e];
}
static __device__ __forceinline__ int edge_col(const void* ei, int i64, int e) {
    return i64 ? (int)((const long long*)ei)[N_EDGES + e] : ((const int*)ei)[N_EDGES + e];
}

__global__ void detect_i64(const int* __restrict__ w, int* __restrict__ flag) {
    __shared__ int red[256];
    int acc = 0;
    // sample odd 32-bit words spread over the first 1.6M elements (safe for both dtypes)
    for (int j = threadIdx.x; j < 2048; j += 256) {
        int k = j * 781;             // max 1,598,707 < 1.6M
        acc |= w[2 * k + 1];
    }
    red[threadIdx.x] = acc;
    __syncthreads();
    for (int off = 128; off > 0; off >>= 1) {
        if (threadIdx.x < off) red[threadIdx.x] |= red[threadIdx.x + off];
        __syncthreads();
    }
    if (threadIdx.x == 0) *flag = (red[0] == 0) ? 1 : 0;
}

// ---------------------------------------------------------------------------
// degree / normalization
// ---------------------------------------------------------------------------
__global__ void zero_i32(int* __restrict__ p, int n) {
    int i = blockIdx.x * blockDim.x + threadIdx.x;
    if (i < n) p[i] = 0;
}

__global__ void count_deg(const void* __restrict__ ei, const int* __restrict__ flag,
                          int* __restrict__ deg) {
    int e = blockIdx.x * blockDim.x + threadIdx.x;
    if (e >= N_EDGES) return;
    int r = edge_row(ei, *flag, e);
    atomicAdd(&deg[r], 1);
}

__global__ void compute_dis(const int* __restrict__ deg, float* __restrict__ dis) {
    int i = blockIdx.x * blockDim.x + threadIdx.x;
    if (i < N_NODES) dis[i] = rsqrtf((float)deg[i] + 1.0f);
}

// ---------------------------------------------------------------------------
// exclusive scan of deg -> row_start (3-kernel, 1024 elems/block)
// ---------------------------------------------------------------------------
__global__ void scan_bsum(const int* __restrict__ deg, int* __restrict__ bsum) {
    __shared__ int sd[256];
    int base = blockIdx.x * 1024;
    int t = threadIdx.x;
    int s = 0;
    for (int j = 0; j < 4; ++j) {
        int idx = base + t + j * 256;
        if (idx < N_NODES) s += deg[idx];
    }
    sd[t] = s;
    __syncthreads();
    for (int off = 128; off > 0; off >>= 1) {
        if (t < off) sd[t] += sd[t + off];
        __syncthreads();
    }
    if (t == 0) bsum[blockIdx.x] = sd[0];
}

__global__ void scan_boff(const int* __restrict__ bsum, int* __restrict__ boff, int nb) {
    __shared__ int sd[128];
    int t = threadIdx.x;
    int v = (t < nb) ? bsum[t] : 0;
    sd[t] = v;
    __syncthreads();
    for (int off = 1; off < 128; off <<= 1) {
        int add = (t >= off) ? sd[t - off] : 0;
        __syncthreads();
        sd[t] += add;
        __syncthreads();
    }
    if (t < nb) boff[t] = sd[t] - v;   // exclusive
}

__global__ void scan_write(const int* __restrict__ deg, const int* __restrict__ boff,
                           int* __restrict__ rowst, int* __restrict__ cursor) {
    __shared__ int ts[256];
    int t = threadIdx.x;
    int base = blockIdx.x * 1024 + t * 4;
    int v[4];
    int s = 0;
    for (int j = 0; j < 4; ++j) {
        int idx = base + j;
        v[j] = (idx < N_NODES) ? deg[idx] : 0;
        s += v[j];
    }
    ts[t] = s;
    __syncthreads();
    int self = s;
    for (int off = 1; off < 256; off <<= 1) {
        int add = (t >= off) ? ts[t - off] : 0;
        __syncthreads();
        ts[t] += add;
        __syncthreads();
    }
    int run = boff[blockIdx.x] + ts[t] - self;
    for (int j = 0; j < 4; ++j) {
        int idx = base + j;
        if (idx < N_NODES) { rowst[idx] = run; cursor[idx] = run; }
        run += v[j];
    }
}

__global__ void fill_csr(const void* __restrict__ ei, const int* __restrict__ flag,
                         const float* __restrict__ dis, int* __restrict__ cursor,
                         int* __restrict__ csr_col, float* __restrict__ csr_nrm) {
    int e = blockIdx.x * blockDim.x + threadIdx.x;
    if (e >= N_EDGES) return;
    int f = *flag;
    int r = edge_row(ei, f, e);
    int c = edge_col(ei, f, e);
    int pos = atomicAdd(&cursor[r], 1);
    csr_col[pos] = c;
    csr_nrm[pos] = dis[r] * dis[c];
}

// ---------------------------------------------------------------------------
// GEMM: out[N x Mfull] = in[N x 128] @ W[128 x Mfull], tile of MT cols/block.
// W tile fully staged in LDS; activations staged half-K, k-major (conflict-free
// broadcasts). Each thread: 4 rows x 4 cols.
// ---------------------------------------------------------------------------
template<int MT, int BLOCK>
__global__ void __launch_bounds__(BLOCK)
gemm_tile(const float* __restrict__ in, const float* __restrict__ W,
          float* __restrict__ out, int Mfull) {
    constexpr int MG = MT / 4;            // float4 col groups
    constexpr int ROWSETS = BLOCK / MG;   // 16
    constexpr int ROWS = ROWSETS * 4;     // 64
    __shared__ float Wl[128 * MT];        // full-K weight tile
    __shared__ float hs[64 * ROWS];       // half-K activations, k-major
    const int tid = threadIdx.x;
    const int c0 = blockIdx.y * MT;
    const int i0 = blockIdx.x * ROWS;

    for (int idx = tid; idx < 128 * MT; idx += BLOCK) {
        int k = idx / MT, m = idx % MT;
        int gm = c0 + m;
        Wl[idx] = (gm < Mfull) ? W[k * Mfull + gm] : 0.0f;
    }

    const int mg = tid % MG, rs = tid / MG;
    float4 acc[4];
    acc[0] = acc[1] = acc[2] = acc[3] = make_float4(0.f, 0.f, 0.f, 0.f);

    for (int kh = 0; kh < 2; ++kh) {
        __syncthreads();
        for (int idx = tid; idx < 16 * ROWS; idx += BLOCK) {
            int kq = idx / ROWS, r = idx % ROWS;
            int gi = i0 + r;
            float4 v = make_float4(0.f, 0.f, 0.f, 0.f);
            if (gi < N_NODES) v = *(const float4*)(in + (size_t)gi * 128 + kh * 64 + kq * 4);
            hs[(kq * 4 + 0) * ROWS + r] = v.x;
            hs[(kq * 4 + 1) * ROWS + r] = v.y;
            hs[(kq * 4 + 2) * ROWS + r] = v.z;
            hs[(kq * 4 + 3) * ROWS + r] = v.w;
        }
        __syncthreads();
        #pragma unroll 16
        for (int k = 0; k < 64; ++k) {
            const float4 w4 = *(const float4*)&Wl[(kh * 64 + k) * MT + mg * 4];
            const float* hp = &hs[k * ROWS + rs * 4];
            #pragma unroll
            for (int rr = 0; rr < 4; ++rr) {
                float h = hp[rr];
                acc[rr].x = fmaf(h, w4.x, acc[rr].x);
                acc[rr].y = fmaf(h, w4.y, acc[rr].y);
                acc[rr].z = fmaf(h, w4.z, acc[rr].z);
                acc[rr].w = fmaf(h, w4.w, acc[rr].w);
            }
        }
    }

    const int gc = c0 + mg * 4;
    #pragma unroll
    for (int rr = 0; rr < 4; ++rr) {
        int gi = i0 + rs * 4 + rr;
        if (gi >= N_NODES) continue;
        if ((Mfull & 3) == 0) {
            *(float4*)(out + (size_t)gi * Mfull + gc) = acc[rr];
        } else {
            float v[4] = {acc[rr].x, acc[rr].y, acc[rr].z, acc[rr].w};
            #pragma unroll
            for (int j = 0; j < 4; ++j)
                if (gc + j < Mfull) out[(size_t)gi * Mfull + gc + j] = v[j];
        }
    }
}

// ---------------------------------------------------------------------------
// CSR aggregation: one wave per node. C=128: lane -> float2 channels.
// out[i] = sum_e norm_e * t[col_e] + dis_i^2 * t[i] + bias  (optional relu)
// ---------------------------------------------------------------------------
__global__ void agg_c128(const float* __restrict__ t, const int* __restrict__ rowst,
                         const int* __restrict__ deg, const int* __restrict__ csr_col,
                         const float* __restrict__ csr_nrm, const float* __restrict__ dis,
                         const float* __restrict__ bias, float* __restrict__ out, int relu) {
    int w = blockIdx.x * (blockDim.x >> 6) + (threadIdx.x >> 6);
    int lane = threadIdx.x & 63;
    if (w >= N_NODES) return;
    int s = rowst[w], d = deg[w];
    float di = dis[w];
    float sn = di * di;
    float2 tv = ((const float2*)(t + (size_t)w * 128))[lane];
    float2 bv = ((const float2*)bias)[lane];
    float ax = fmaf(sn, tv.x, bv.x);
    float ay = fmaf(sn, tv.y, bv.y);
    for (int j = s; j < s + d; ++j) {
        int c = csr_col[j];
        float nrm = csr_nrm[j];
        float2 v = ((const float2*)(t + (size_t)c * 128))[lane];
        ax = fmaf(nrm, v.x, ax);
        ay = fmaf(nrm, v.y, ay);
    }
    if (relu) { ax = fmaxf(ax, 0.f); ay = fmaxf(ay, 0.f); }
    ((float2*)(out + (size_t)w * 128))[lane] = make_float2(ax, ay);
}

__global__ void agg_c47(const float* __restrict__ t, const int* __restrict__ rowst,
                        const int* __restrict__ deg, const int* __restrict__ csr_col,
                        const float* __restrict__ csr_nrm, const float* __restrict__ dis,
                        const float* __restrict__ bias, float* __restrict__ out) {
    int w = blockIdx.x * (blockDim.x >> 6) + (threadIdx.x >> 6);
    int lane = threadIdx.x & 63;
    if (w >= N_NODES) return;
    int s = rowst[w], d = deg[w];
    float di = dis[w];
    float sn = di * di;
    float acc = 0.f;
    if (lane < 47) acc = fmaf(sn, t[(size_t)w * 47 + lane], bias[lane]);
    for (int j = s; j < s + d; ++j) {
        int c = csr_col[j];
        float nrm = csr_nrm[j];
        if (lane < 47) acc = fmaf(nrm, t[(size_t)c * 47 + lane], acc);
    }
    if (lane < 47) out[(size_t)w * 47 + lane] = acc;
}

// ---------------------------------------------------------------------------
extern "C" void kernel_launch(void* const* d_in, const int* in_sizes, int n_in,
                              void* d_out, int out_size, void* d_ws, size_t ws_size,
                              hipStream_t stream) {
    const float* x  = (const float*)d_in[0];
    const void*  ei = d_in[1];
    // d_in[2] = edge_attr, unused by the reference forward
    const float* W1 = (const float*)d_in[3];
    const float* b1 = (const float*)d_in[4];
    const float* W2 = (const float*)d_in[5];
    const float* b2 = (const float*)d_in[6];
    const float* W3 = (const float*)d_in[7];
    const float* b3 = (const float*)d_in[8];
    float* out = (float*)d_out;

    size_t off = 0;
    auto alloc = [&](size_t bytes) -> void* {
        void* p = (char*)d_ws + off;
        off += (bytes + 511) & ~(size_t)511;
        return p;
    };
    float* dis     = (float*)alloc((size_t)N_NODES * 4);
    int*   deg     = (int*)  alloc((size_t)N_NODES * 4);
    int*   rowst   = (int*)  alloc((size_t)N_NODES * 4);
    int*   cursor  = (int*)  alloc((size_t)N_NODES * 4);
    int*   bsum    = (int*)  alloc(128 * 4);
    int*   boff    = (int*)  alloc(128 * 4);
    int*   flag    = (int*)  alloc(64);
    int*   csr_col = (int*)  alloc((size_t)N_EDGES * 4);
    float* csr_nrm = (float*)alloc((size_t)N_EDGES * 4);
    float* bufA    = (float*)alloc((size_t)N_NODES * 128 * 4);
    float* bufB    = (float*)alloc((size_t)N_NODES * 128 * 4);
    (void)ws_size; (void)in_sizes; (void)n_in; (void)out_size;

    // --- graph preprocessing (per launch; ws is re-poisoned each call) ---
    detect_i64<<<1, 256, 0, stream>>>((const int*)ei, flag);
    zero_i32<<<(N_NODES + 255) / 256, 256, 0, stream>>>(deg, N_NODES);
    count_deg<<<N_EDGES / 256, 256, 0, stream>>>(ei, flag, deg);
    compute_dis<<<(N_NODES + 255) / 256, 256, 0, stream>>>(deg, dis);
    int nb = (N_NODES + 1023) / 1024;   // 98
    scan_bsum<<<nb, 256, 0, stream>>>(deg, bsum);
    scan_boff<<<1, 128, 0, stream>>>(bsum, boff, nb);
    scan_write<<<nb, 256, 0, stream>>>(deg, boff, rowst, cursor);
    fill_csr<<<N_EDGES / 256, 256, 0, stream>>>(ei, flag, dis, cursor, csr_col, csr_nrm);

    // --- layer 1: t = x@W1 ; h1 = relu(agg) ---
    dim3 g128((N_NODES + 63) / 64, 2);
    gemm_tile<64, 256><<<g128, 256, 0, stream>>>(x, W1, bufA, 128);
    agg_c128<<<(N_NODES + 3) / 4, 256, 0, stream>>>(bufA, rowst, deg, csr_col, csr_nrm, dis, b1, bufB, 1);
    // --- layer 2 ---
    gemm_tile<64, 256><<<g128, 256, 0, stream>>>(bufB, W2, bufA, 128);
    agg_c128<<<(N_NODES + 3) / 4, 256, 0, stream>>>(bufA, rowst, deg, csr_col, csr_nrm, dis, b2, bufB, 1);
    // --- layer 3 (47 cols, no relu) ---
    dim3 g47((N_NODES + 63) / 64, 1);
    gemm_tile<48, 192><<<g47, 192, 0, stream>>>(bufB, W3, bufA, 47);
    agg_c47<<<(N_NODES + 3) / 4, 256, 0, stream>>>(bufA, rowst, deg, csr_col, csr_nrm, dis, b3, out);
}

// Round 2
// 866.931 us; speedup vs baseline: 1.2325x; 1.2325x over previous
//
#include <hip/hip_runtime.h>
#include <cstdint>
#include <cstddef>

#define N_NODES 100000
#define N_EDGES 1600000

// ---------------------------------------------------------------------------
// edge_index dtype handling: JAX requests int64 but (with x64 disabled) may
// deliver int32. Detect on-device: for int64, the high 32-bit word of every
// element is 0 (values in [0,1e5)); for int32, odd words are random values.
// ---------------------------------------------------------------------------
static __device__ __forceinline__ int edge_row(const void* ei, int i64, int e) {
    return i64 ? (int)((const long long*)ei)[e] : ((const int*)ei)[e];
}
static __device__ __forceinline__ int edge_col(const void* ei, int i64, int e) {
    return i64 ? (int)((const long long*)ei)[N_EDGES + e] : ((const int*)ei)[N_EDGES + e];
}

__global__ void detect_i64(const int* __restrict__ w, int* __restrict__ flag) {
    __shared__ int red[256];
    int acc = 0;
    for (int j = threadIdx.x; j < 2048; j += 256) {
        int k = j * 781;             // max 1,598,707 < 1.6M
        acc |= w[2 * k + 1];
    }
    red[threadIdx.x] = acc;
    __syncthreads();
    for (int off = 128; off > 0; off >>= 1) {
        if (threadIdx.x < off) red[threadIdx.x] |= red[threadIdx.x + off];
        __syncthreads();
    }
    if (threadIdx.x == 0) *flag = (red[0] == 0) ? 1 : 0;
}

// ---------------------------------------------------------------------------
// degree / normalization
// ---------------------------------------------------------------------------
__global__ void zero_i32(int* __restrict__ p, int n) {
    int i = blockIdx.x * blockDim.x + threadIdx.x;
    if (i < n) p[i] = 0;
}

__global__ void count_deg(const void* __restrict__ ei, const int* __restrict__ flag,
                          int* __restrict__ deg) {
    int e = blockIdx.x * blockDim.x + threadIdx.x;
    if (e >= N_EDGES) return;
    int r = edge_row(ei, *flag, e);
    atomicAdd(&deg[r], 1);
}

__global__ void compute_dis(const int* __restrict__ deg, float* __restrict__ dis) {
    int i = blockIdx.x * blockDim.x + threadIdx.x;
    if (i < N_NODES) dis[i] = rsqrtf((float)deg[i] + 1.0f);
}

// ---------------------------------------------------------------------------
// exclusive scan of deg -> row_start (3-kernel, 1024 elems/block)
// ---------------------------------------------------------------------------
__global__ void scan_bsum(const int* __restrict__ deg, int* __restrict__ bsum) {
    __shared__ int sd[256];
    int base = blockIdx.x * 1024;
    int t = threadIdx.x;
    int s = 0;
    for (int j = 0; j < 4; ++j) {
        int idx = base + t + j * 256;
        if (idx < N_NODES) s += deg[idx];
    }
    sd[t] = s;
    __syncthreads();
    for (int off = 128; off > 0; off >>= 1) {
        if (t < off) sd[t] += sd[t + off];
        __syncthreads();
    }
    if (t == 0) bsum[blockIdx.x] = sd[0];
}

__global__ void scan_boff(const int* __restrict__ bsum, int* __restrict__ boff, int nb) {
    __shared__ int sd[128];
    int t = threadIdx.x;
    int v = (t < nb) ? bsum[t] : 0;
    sd[t] = v;
    __syncthreads();
    for (int off = 1; off < 128; off <<= 1) {
        int add = (t >= off) ? sd[t - off] : 0;
        __syncthreads();
        sd[t] += add;
        __syncthreads();
    }
    if (t < nb) boff[t] = sd[t] - v;   // exclusive
}

__global__ void scan_write(const int* __restrict__ deg, const int* __restrict__ boff,
                           int* __restrict__ rowst, int* __restrict__ cursor) {
    __shared__ int ts[256];
    int t = threadIdx.x;
    int base = blockIdx.x * 1024 + t * 4;
    int v[4];
    int s = 0;
    for (int j = 0; j < 4; ++j) {
        int idx = base + j;
        v[j] = (idx < N_NODES) ? deg[idx] : 0;
        s += v[j];
    }
    ts[t] = s;
    __syncthreads();
    int self = s;
    for (int off = 1; off < 256; off <<= 1) {
        int add = (t >= off) ? ts[t - off] : 0;
        __syncthreads();
        ts[t] += add;
        __syncthreads();
    }
    int run = boff[blockIdx.x] + ts[t] - self;
    for (int j = 0; j < 4; ++j) {
        int idx = base + j;
        if (idx < N_NODES) { rowst[idx] = run; cursor[idx] = run; }
        run += v[j];
    }
}

// packed CSR entry: .x = col, .y = norm (bit-cast float)
__global__ void fill_csr(const void* __restrict__ ei, const int* __restrict__ flag,
                         const float* __restrict__ dis, int* __restrict__ cursor,
                         int2* __restrict__ csr_cn) {
    int e = blockIdx.x * blockDim.x + threadIdx.x;
    if (e >= N_EDGES) return;
    int f = *flag;
    int r = edge_row(ei, f, e);
    int c = edge_col(ei, f, e);
    int pos = atomicAdd(&cursor[r], 1);
    csr_cn[pos] = make_int2(c, __float_as_int(dis[r] * dis[c]));
}

// ---------------------------------------------------------------------------
// GEMM: out[N x Mfull] = in[N x 128] @ W[128 x Mfull], tile of MT cols/block.
// ---------------------------------------------------------------------------
template<int MT, int BLOCK>
__global__ void __launch_bounds__(BLOCK)
gemm_tile(const float* __restrict__ in, const float* __restrict__ W,
          float* __restrict__ out, int Mfull) {
    constexpr int MG = MT / 4;            // float4 col groups
    constexpr int ROWSETS = BLOCK / MG;   // 16
    constexpr int ROWS = ROWSETS * 4;     // 64
    __shared__ float Wl[128 * MT];        // full-K weight tile
    __shared__ float hs[64 * ROWS];       // half-K activations, k-major
    const int tid = threadIdx.x;
    const int c0 = blockIdx.y * MT;
    const int i0 = blockIdx.x * ROWS;

    for (int idx = tid; idx < 128 * MT; idx += BLOCK) {
        int k = idx / MT, m = idx % MT;
        int gm = c0 + m;
        Wl[idx] = (gm < Mfull) ? W[k * Mfull + gm] : 0.0f;
    }

    const int mg = tid % MG, rs = tid / MG;
    float4 acc[4];
    acc[0] = acc[1] = acc[2] = acc[3] = make_float4(0.f, 0.f, 0.f, 0.f);

    for (int kh = 0; kh < 2; ++kh) {
        __syncthreads();
        for (int idx = tid; idx < 16 * ROWS; idx += BLOCK) {
            int kq = idx / ROWS, r = idx % ROWS;
            int gi = i0 + r;
            float4 v = make_float4(0.f, 0.f, 0.f, 0.f);
            if (gi < N_NODES) v = *(const float4*)(in + (size_t)gi * 128 + kh * 64 + kq * 4);
            hs[(kq * 4 + 0) * ROWS + r] = v.x;
            hs[(kq * 4 + 1) * ROWS + r] = v.y;
            hs[(kq * 4 + 2) * ROWS + r] = v.z;
            hs[(kq * 4 + 3) * ROWS + r] = v.w;
        }
        __syncthreads();
        #pragma unroll 16
        for (int k = 0; k < 64; ++k) {
            const float4 w4 = *(const float4*)&Wl[(kh * 64 + k) * MT + mg * 4];
            const float* hp = &hs[k * ROWS + rs * 4];
            #pragma unroll
            for (int rr = 0; rr < 4; ++rr) {
                float h = hp[rr];
                acc[rr].x = fmaf(h, w4.x, acc[rr].x);
                acc[rr].y = fmaf(h, w4.y, acc[rr].y);
                acc[rr].z = fmaf(h, w4.z, acc[rr].z);
                acc[rr].w = fmaf(h, w4.w, acc[rr].w);
            }
        }
    }

    const int gc = c0 + mg * 4;
    #pragma unroll
    for (int rr = 0; rr < 4; ++rr) {
        int gi = i0 + rs * 4 + rr;
        if (gi >= N_NODES) continue;
        if ((Mfull & 3) == 0) {
            *(float4*)(out + (size_t)gi * Mfull + gc) = acc[rr];
        } else {
            float v[4] = {acc[rr].x, acc[rr].y, acc[rr].z, acc[rr].w};
            #pragma unroll
            for (int j = 0; j < 4; ++j)
                if (gc + j < Mfull) out[(size_t)gi * Mfull + gc + j] = v[j];
        }
    }
}

// ---------------------------------------------------------------------------
// CSR aggregation, software-pipelined 4-wide: prefetch next 4 packed (col,nrm)
// entries while 4 row-gathers for the current group are in flight.
// out[i] = sum_e nrm_e * t[col_e] + dis_i^2 * t[i] + bias  (optional relu)
// ---------------------------------------------------------------------------
__global__ void agg_c128(const float* __restrict__ t, const int* __restrict__ rowst,
                         const int* __restrict__ deg, const int2* __restrict__ cn,
                         const float* __restrict__ dis, const float* __restrict__ bias,
                         float* __restrict__ out, int relu) {
    int w = blockIdx.x * (blockDim.x >> 6) + (threadIdx.x >> 6);
    int lane = threadIdx.x & 63;
    if (w >= N_NODES) return;
    int s = rowst[w], d = deg[w];
    float di = dis[w];
    float sn = di * di;
    float2 tv = ((const float2*)(t + (size_t)w * 128))[lane];
    float2 bv = ((const float2*)bias)[lane];
    float ax = fmaf(sn, tv.x, bv.x);
    float ay = fmaf(sn, tv.y, bv.y);
    int e = s + d;
    int j = s;
    if (j + 4 <= e) {
        int2 c0 = cn[j], c1 = cn[j + 1], c2 = cn[j + 2], c3 = cn[j + 3];
        j += 4;
        while (j + 4 <= e) {
            int2 n0 = cn[j], n1 = cn[j + 1], n2 = cn[j + 2], n3 = cn[j + 3];
            float2 v0 = ((const float2*)(t + (size_t)c0.x * 128))[lane];
            float2 v1 = ((const float2*)(t + (size_t)c1.x * 128))[lane];
            float2 v2 = ((const float2*)(t + (size_t)c2.x * 128))[lane];
            float2 v3 = ((const float2*)(t + (size_t)c3.x * 128))[lane];
            float w0 = __int_as_float(c0.y), w1 = __int_as_float(c1.y);
            float w2 = __int_as_float(c2.y), w3 = __int_as_float(c3.y);
            ax = fmaf(w0, v0.x, ax); ay = fmaf(w0, v0.y, ay);
            ax = fmaf(w1, v1.x, ax); ay = fmaf(w1, v1.y, ay);
            ax = fmaf(w2, v2.x, ax); ay = fmaf(w2, v2.y, ay);
            ax = fmaf(w3, v3.x, ax); ay = fmaf(w3, v3.y, ay);
            c0 = n0; c1 = n1; c2 = n2; c3 = n3;
            j += 4;
        }
        float2 v0 = ((const float2*)(t + (size_t)c0.x * 128))[lane];
        float2 v1 = ((const float2*)(t + (size_t)c1.x * 128))[lane];
        float2 v2 = ((const float2*)(t + (size_t)c2.x * 128))[lane];
        float2 v3 = ((const float2*)(t + (size_t)c3.x * 128))[lane];
        float w0 = __int_as_float(c0.y), w1 = __int_as_float(c1.y);
        float w2 = __int_as_float(c2.y), w3 = __int_as_float(c3.y);
        ax = fmaf(w0, v0.x, ax); ay = fmaf(w0, v0.y, ay);
        ax = fmaf(w1, v1.x, ax); ay = fmaf(w1, v1.y, ay);
        ax = fmaf(w2, v2.x, ax); ay = fmaf(w2, v2.y, ay);
        ax = fmaf(w3, v3.x, ax); ay = fmaf(w3, v3.y, ay);
    }
    for (; j < e; ++j) {
        int2 c = cn[j];
        float2 v = ((const float2*)(t + (size_t)c.x * 128))[lane];
        float nrm = __int_as_float(c.y);
        ax = fmaf(nrm, v.x, ax);
        ay = fmaf(nrm, v.y, ay);
    }
    if (relu) { ax = fmaxf(ax, 0.f); ay = fmaxf(ay, 0.f); }
    ((float2*)(out + (size_t)w * 128))[lane] = make_float2(ax, ay);
}

__global__ void agg_c47(const float* __restrict__ t, const int* __restrict__ rowst,
                        const int* __restrict__ deg, const int2* __restrict__ cn,
                        const float* __restrict__ dis, const float* __restrict__ bias,
                        float* __restrict__ out) {
    int w = blockIdx.x * (blockDim.x >> 6) + (threadIdx.x >> 6);
    int lane = threadIdx.x & 63;
    if (w >= N_NODES) return;
    int s = rowst[w], d = deg[w];
    float di = dis[w];
    float sn = di * di;
    bool act = lane < 47;
    int li = act ? lane : 0;
    float acc = act ? fmaf(sn, t[(size_t)w * 47 + li], bias[li]) : 0.f;
    int e = s + d;
    int j = s;
    if (j + 4 <= e) {
        int2 c0 = cn[j], c1 = cn[j + 1], c2 = cn[j + 2], c3 = cn[j + 3];
        j += 4;
        while (j + 4 <= e) {
            int2 n0 = cn[j], n1 = cn[j + 1], n2 = cn[j + 2], n3 = cn[j + 3];
            float v0 = t[(size_t)c0.x * 47 + li];
            float v1 = t[(size_t)c1.x * 47 + li];
            float v2 = t[(size_t)c2.x * 47 + li];
            float v3 = t[(size_t)c3.x * 47 + li];
            acc = fmaf(__int_as_float(c0.y), v0, acc);
            acc = fmaf(__int_as_float(c1.y), v1, acc);
            acc = fmaf(__int_as_float(c2.y), v2, acc);
            acc = fmaf(__int_as_float(c3.y), v3, acc);
            c0 = n0; c1 = n1; c2 = n2; c3 = n3;
            j += 4;
        }
        float v0 = t[(size_t)c0.x * 47 + li];
        float v1 = t[(size_t)c1.x * 47 + li];
        float v2 = t[(size_t)c2.x * 47 + li];
        float v3 = t[(size_t)c3.x * 47 + li];
        acc = fmaf(__int_as_float(c0.y), v0, acc);
        acc = fmaf(__int_as_float(c1.y), v1, acc);
        acc = fmaf(__int_as_float(c2.y), v2, acc);
        acc = fmaf(__int_as_float(c3.y), v3, acc);
    }
    for (; j < e; ++j) {
        int2 c = cn[j];
        float v = t[(size_t)c.x * 47 + li];
        acc = fmaf(__int_as_float(c.y), v, acc);
    }
    if (act) out[(size_t)w * 47 + lane] = acc;
}

// ---------------------------------------------------------------------------
extern "C" void kernel_launch(void* const* d_in, const int* in_sizes, int n_in,
                              void* d_out, int out_size, void* d_ws, size_t ws_size,
                              hipStream_t stream) {
    const float* x  = (const float*)d_in[0];
    const void*  ei = d_in[1];
    // d_in[2] = edge_attr, unused by the reference forward
    const float* W1 = (const float*)d_in[3];
    const float* b1 = (const float*)d_in[4];
    const float* W2 = (const float*)d_in[5];
    const float* b2 = (const float*)d_in[6];
    const float* W3 = (const float*)d_in[7];
    const float* b3 = (const float*)d_in[8];
    float* out = (float*)d_out;

    size_t off = 0;
    auto alloc = [&](size_t bytes) -> void* {
        void* p = (char*)d_ws + off;
        off += (bytes + 511) & ~(size_t)511;
        return p;
    };
    float* dis     = (float*)alloc((size_t)N_NODES * 4);
    int*   deg     = (int*)  alloc((size_t)N_NODES * 4);
    int*   rowst   = (int*)  alloc((size_t)N_NODES * 4);
    int*   cursor  = (int*)  alloc((size_t)N_NODES * 4);
    int*   bsum    = (int*)  alloc(128 * 4);
    int*   boff    = (int*)  alloc(128 * 4);
    int*   flag    = (int*)  alloc(64);
    int2*  csr_cn  = (int2*) alloc((size_t)N_EDGES * 8);
    float* bufA    = (float*)alloc((size_t)N_NODES * 128 * 4);
    float* bufB    = (float*)alloc((size_t)N_NODES * 128 * 4);
    (void)ws_size; (void)in_sizes; (void)n_in; (void)out_size;

    // --- graph preprocessing (per launch; ws is re-poisoned each call) ---
    detect_i64<<<1, 256, 0, stream>>>((const int*)ei, flag);
    zero_i32<<<(N_NODES + 255) / 256, 256, 0, stream>>>(deg, N_NODES);
    count_deg<<<N_EDGES / 256, 256, 0, stream>>>(ei, flag, deg);
    compute_dis<<<(N_NODES + 255) / 256, 256, 0, stream>>>(deg, dis);
    int nb = (N_NODES + 1023) / 1024;   // 98
    scan_bsum<<<nb, 256, 0, stream>>>(deg, bsum);
    scan_boff<<<1, 128, 0, stream>>>(bsum, boff, nb);
    scan_write<<<nb, 256, 0, stream>>>(deg, boff, rowst, cursor);
    fill_csr<<<N_EDGES / 256, 256, 0, stream>>>(ei, flag, dis, cursor, csr_cn);

    // --- layer 1: t = x@W1 ; h1 = relu(agg) ---
    dim3 g128((N_NODES + 63) / 64, 2);
    gemm_tile<64, 256><<<g128, 256, 0, stream>>>(x, W1, bufA, 128);
    agg_c128<<<(N_NODES + 3) / 4, 256, 0, stream>>>(bufA, rowst, deg, csr_cn, dis, b1, bufB, 1);
    // --- layer 2 ---
    gemm_tile<64, 256><<<g128, 256, 0, stream>>>(bufB, W2, bufA, 128);
    agg_c128<<<(N_NODES + 3) / 4, 256, 0, stream>>>(bufA, rowst, deg, csr_cn, dis, b2, bufB, 1);
    // --- layer 3 (47 cols, no relu) ---
    dim3 g47((N_NODES + 63) / 64, 1);
    gemm_tile<48, 192><<<g47, 192, 0, stream>>>(bufB, W3, bufA, 47);
    agg_c47<<<(N_NODES + 3) / 4, 256, 0, stream>>>(bufA, rowst, deg, csr_cn, dis, b3, out);
}

// Round 3
// 757.487 us; speedup vs baseline: 1.4106x; 1.1445x over previous
//
#include <hip/hip_runtime.h>
#include <hip/hip_fp16.h>
#include <cstdint>
#include <cstddef>

#define N_NODES 100000
#define N_EDGES 1600000

// ---------------------------------------------------------------------------
// edge_index dtype handling: JAX requests int64 but (with x64 disabled) may
// deliver int32. Detect on-device: for int64, the high 32-bit word of every
// element is 0 (values in [0,1e5)); for int32, odd words are random values.
// ---------------------------------------------------------------------------
static __device__ __forceinline__ int edge_row(const void* ei, int i64, int e) {
    return i64 ? (int)((const long long*)ei)[e] : ((const int*)ei)[e];
}
static __device__ __forceinline__ int edge_col(const void* ei, int i64, int e) {
    return i64 ? (int)((const long long*)ei)[N_EDGES + e] : ((const int*)ei)[N_EDGES + e];
}

__global__ void detect_i64(const int* __restrict__ w, int* __restrict__ flag) {
    __shared__ int red[256];
    int acc = 0;
    for (int j = threadIdx.x; j < 2048; j += 256) {
        int k = j * 781;             // max 1,598,707 < 1.6M
        acc |= w[2 * k + 1];
    }
    red[threadIdx.x] = acc;
    __syncthreads();
    for (int off = 128; off > 0; off >>= 1) {
        if (threadIdx.x < off) red[threadIdx.x] |= red[threadIdx.x + off];
        __syncthreads();
    }
    if (threadIdx.x == 0) *flag = (red[0] == 0) ? 1 : 0;
}

// ---------------------------------------------------------------------------
// degree / normalization
// ---------------------------------------------------------------------------
__global__ void zero_i32(int* __restrict__ p, int n) {
    int i = blockIdx.x * blockDim.x + threadIdx.x;
    if (i < n) p[i] = 0;
}

__global__ void count_deg(const void* __restrict__ ei, const int* __restrict__ flag,
                          int* __restrict__ deg) {
    int e = blockIdx.x * blockDim.x + threadIdx.x;
    if (e >= N_EDGES) return;
    int r = edge_row(ei, *flag, e);
    atomicAdd(&deg[r], 1);
}

__global__ void compute_dis(const int* __restrict__ deg, float* __restrict__ dis) {
    int i = blockIdx.x * blockDim.x + threadIdx.x;
    if (i < N_NODES) dis[i] = rsqrtf((float)deg[i] + 1.0f);
}

// ---------------------------------------------------------------------------
// exclusive scan of deg -> row_start (3-kernel, 1024 elems/block)
// ---------------------------------------------------------------------------
__global__ void scan_bsum(const int* __restrict__ deg, int* __restrict__ bsum) {
    __shared__ int sd[256];
    int base = blockIdx.x * 1024;
    int t = threadIdx.x;
    int s = 0;
    for (int j = 0; j < 4; ++j) {
        int idx = base + t + j * 256;
        if (idx < N_NODES) s += deg[idx];
    }
    sd[t] = s;
    __syncthreads();
    for (int off = 128; off > 0; off >>= 1) {
        if (t < off) sd[t] += sd[t + off];
        __syncthreads();
    }
    if (t == 0) bsum[blockIdx.x] = sd[0];
}

__global__ void scan_boff(const int* __restrict__ bsum, int* __restrict__ boff, int nb) {
    __shared__ int sd[128];
    int t = threadIdx.x;
    int v = (t < nb) ? bsum[t] : 0;
    sd[t] = v;
    __syncthreads();
    for (int off = 1; off < 128; off <<= 1) {
        int add = (t >= off) ? sd[t - off] : 0;
        __syncthreads();
        sd[t] += add;
        __syncthreads();
    }
    if (t < nb) boff[t] = sd[t] - v;   // exclusive
}

__global__ void scan_write(const int* __restrict__ deg, const int* __restrict__ boff,
                           int* __restrict__ rowst, int* __restrict__ cursor) {
    __shared__ int ts[256];
    int t = threadIdx.x;
    int base = blockIdx.x * 1024 + t * 4;
    int v[4];
    int s = 0;
    for (int j = 0; j < 4; ++j) {
        int idx = base + j;
        v[j] = (idx < N_NODES) ? deg[idx] : 0;
        s += v[j];
    }
    ts[t] = s;
    __syncthreads();
    int self = s;
    for (int off = 1; off < 256; off <<= 1) {
        int add = (t >= off) ? ts[t - off] : 0;
        __syncthreads();
        ts[t] += add;
        __syncthreads();
    }
    int run = boff[blockIdx.x] + ts[t] - self;
    for (int j = 0; j < 4; ++j) {
        int idx = base + j;
        if (idx < N_NODES) { rowst[idx] = run; cursor[idx] = run; }
        run += v[j];
    }
}

// packed CSR entry: .x = col, .y = norm (bit-cast float)
__global__ void fill_csr(const void* __restrict__ ei, const int* __restrict__ flag,
                         const float* __restrict__ dis, int* __restrict__ cursor,
                         int2* __restrict__ csr_cn) {
    int e = blockIdx.x * blockDim.x + threadIdx.x;
    if (e >= N_EDGES) return;
    int f = *flag;
    int r = edge_row(ei, f, e);
    int c = edge_col(ei, f, e);
    int pos = atomicAdd(&cursor[r], 1);
    csr_cn[pos] = make_int2(c, __float_as_int(dis[r] * dis[c]));
}

// ---------------------------------------------------------------------------
// GEMM: out[N x Mfull] = in[N x 128] @ W[128 x Mfull], tile of MT cols/block.
// fp32 input & accumulation; output templated (fp16 for the t buffers).
// ---------------------------------------------------------------------------
template<typename TOut>
static __device__ __forceinline__ void store4(TOut* p, float4 v);
template<>
__device__ __forceinline__ void store4<float>(float* p, float4 v) {
    *(float4*)p = v;
}
template<>
__device__ __forceinline__ void store4<__half>(__half* p, float4 v) {
    ((__half2*)p)[0] = __float22half2_rn(make_float2(v.x, v.y));
    ((__half2*)p)[1] = __float22half2_rn(make_float2(v.z, v.w));
}

template<typename TOut, int MT, int BLOCK>
__global__ void __launch_bounds__(BLOCK)
gemm_tile(const float* __restrict__ in, const float* __restrict__ W,
          TOut* __restrict__ out, int Mfull) {
    constexpr int MG = MT / 4;            // float4 col groups
    constexpr int ROWSETS = BLOCK / MG;   // 16
    constexpr int ROWS = ROWSETS * 4;     // 64
    __shared__ float Wl[128 * MT];        // full-K weight tile
    __shared__ float hs[64 * ROWS];       // half-K activations, k-major
    const int tid = threadIdx.x;
    const int c0 = blockIdx.y * MT;
    const int i0 = blockIdx.x * ROWS;

    for (int idx = tid; idx < 128 * MT; idx += BLOCK) {
        int k = idx / MT, m = idx % MT;
        int gm = c0 + m;
        Wl[idx] = (gm < Mfull) ? W[k * Mfull + gm] : 0.0f;
    }

    const int mg = tid % MG, rs = tid / MG;
    float4 acc[4];
    acc[0] = acc[1] = acc[2] = acc[3] = make_float4(0.f, 0.f, 0.f, 0.f);

    for (int kh = 0; kh < 2; ++kh) {
        __syncthreads();
        for (int idx = tid; idx < 16 * ROWS; idx += BLOCK) {
            int kq = idx / ROWS, r = idx % ROWS;
            int gi = i0 + r;
            float4 v = make_float4(0.f, 0.f, 0.f, 0.f);
            if (gi < N_NODES) v = *(const float4*)(in + (size_t)gi * 128 + kh * 64 + kq * 4);
            hs[(kq * 4 + 0) * ROWS + r] = v.x;
            hs[(kq * 4 + 1) * ROWS + r] = v.y;
            hs[(kq * 4 + 2) * ROWS + r] = v.z;
            hs[(kq * 4 + 3) * ROWS + r] = v.w;
        }
        __syncthreads();
        #pragma unroll 16
        for (int k = 0; k < 64; ++k) {
            const float4 w4 = *(const float4*)&Wl[(kh * 64 + k) * MT + mg * 4];
            const float* hp = &hs[k * ROWS + rs * 4];
            #pragma unroll
            for (int rr = 0; rr < 4; ++rr) {
                float h = hp[rr];
                acc[rr].x = fmaf(h, w4.x, acc[rr].x);
                acc[rr].y = fmaf(h, w4.y, acc[rr].y);
                acc[rr].z = fmaf(h, w4.z, acc[rr].z);
                acc[rr].w = fmaf(h, w4.w, acc[rr].w);
            }
        }
    }

    const int gc = c0 + mg * 4;
    #pragma unroll
    for (int rr = 0; rr < 4; ++rr) {
        int gi = i0 + rs * 4 + rr;
        if (gi >= N_NODES) continue;
        if ((Mfull & 3) == 0) {
            store4<TOut>(out + (size_t)gi * Mfull + gc, acc[rr]);
        } else {
            float v[4] = {acc[rr].x, acc[rr].y, acc[rr].z, acc[rr].w};
            #pragma unroll
            for (int j = 0; j < 4; ++j)
                if (gc + j < Mfull) out[(size_t)gi * Mfull + gc + j] = (TOut)v[j];
        }
    }
}

// ---------------------------------------------------------------------------
// CSR aggregation over fp16 t rows, software-pipelined 6-wide.
// out[i] = sum_e nrm_e * t[col_e] + dis_i^2 * t[i] + bias  (optional relu)
// ---------------------------------------------------------------------------
#define AGG_DEPTH 6

__global__ void agg_c128(const __half* __restrict__ t, const int* __restrict__ rowst,
                         const int* __restrict__ deg, const int2* __restrict__ cn,
                         const float* __restrict__ dis, const float* __restrict__ bias,
                         float* __restrict__ out, int relu) {
    int w = blockIdx.x * (blockDim.x >> 6) + (threadIdx.x >> 6);
    int lane = threadIdx.x & 63;
    if (w >= N_NODES) return;
    int s = rowst[w], d = deg[w];
    float di = dis[w];
    float sn = di * di;
    float2 tv = __half22float2(((const __half2*)(t + (size_t)w * 128))[lane]);
    float2 bv = ((const float2*)bias)[lane];
    float ax = fmaf(sn, tv.x, bv.x);
    float ay = fmaf(sn, tv.y, bv.y);
    int e = s + d;
    int j = s;
    if (j + AGG_DEPTH <= e) {
        int2 c[AGG_DEPTH];
        #pragma unroll
        for (int q = 0; q < AGG_DEPTH; ++q) c[q] = cn[j + q];
        j += AGG_DEPTH;
        while (j + AGG_DEPTH <= e) {
            int2 n[AGG_DEPTH];
            #pragma unroll
            for (int q = 0; q < AGG_DEPTH; ++q) n[q] = cn[j + q];
            __half2 v[AGG_DEPTH];
            #pragma unroll
            for (int q = 0; q < AGG_DEPTH; ++q)
                v[q] = ((const __half2*)(t + (size_t)c[q].x * 128))[lane];
            #pragma unroll
            for (int q = 0; q < AGG_DEPTH; ++q) {
                float2 f = __half22float2(v[q]);
                float nw = __int_as_float(c[q].y);
                ax = fmaf(nw, f.x, ax);
                ay = fmaf(nw, f.y, ay);
            }
            #pragma unroll
            for (int q = 0; q < AGG_DEPTH; ++q) c[q] = n[q];
            j += AGG_DEPTH;
        }
        #pragma unroll
        for (int q = 0; q < AGG_DEPTH; ++q) {
            __half2 vv = ((const __half2*)(t + (size_t)c[q].x * 128))[lane];
            float2 f = __half22float2(vv);
            float nw = __int_as_float(c[q].y);
            ax = fmaf(nw, f.x, ax);
            ay = fmaf(nw, f.y, ay);
        }
    }
    for (; j < e; ++j) {
        int2 c = cn[j];
        float2 f = __half22float2(((const __half2*)(t + (size_t)c.x * 128))[lane]);
        float nw = __int_as_float(c.y);
        ax = fmaf(nw, f.x, ax);
        ay = fmaf(nw, f.y, ay);
    }
    if (relu) { ax = fmaxf(ax, 0.f); ay = fmaxf(ay, 0.f); }
    ((float2*)(out + (size_t)w * 128))[lane] = make_float2(ax, ay);
}

__global__ void agg_c47(const __half* __restrict__ t, const int* __restrict__ rowst,
                        const int* __restrict__ deg, const int2* __restrict__ cn,
                        const float* __restrict__ dis, const float* __restrict__ bias,
                        float* __restrict__ out) {
    int w = blockIdx.x * (blockDim.x >> 6) + (threadIdx.x >> 6);
    int lane = threadIdx.x & 63;
    if (w >= N_NODES) return;
    int s = rowst[w], d = deg[w];
    float di = dis[w];
    float sn = di * di;
    bool act = lane < 47;
    int li = act ? lane : 0;
    float acc = act ? fmaf(sn, (float)t[(size_t)w * 47 + li], bias[li]) : 0.f;
    int e = s + d;
    int j = s;
    if (j + AGG_DEPTH <= e) {
        int2 c[AGG_DEPTH];
        #pragma unroll
        for (int q = 0; q < AGG_DEPTH; ++q) c[q] = cn[j + q];
        j += AGG_DEPTH;
        while (j + AGG_DEPTH <= e) {
            int2 n[AGG_DEPTH];
            #pragma unroll
            for (int q = 0; q < AGG_DEPTH; ++q) n[q] = cn[j + q];
            __half v[AGG_DEPTH];
            #pragma unroll
            for (int q = 0; q < AGG_DEPTH; ++q)
                v[q] = t[(size_t)c[q].x * 47 + li];
            #pragma unroll
            for (int q = 0; q < AGG_DEPTH; ++q)
                acc = fmaf(__int_as_float(c[q].y), (float)v[q], acc);
            #pragma unroll
            for (int q = 0; q < AGG_DEPTH; ++q) c[q] = n[q];
            j += AGG_DEPTH;
        }
        #pragma unroll
        for (int q = 0; q < AGG_DEPTH; ++q)
            acc = fmaf(__int_as_float(c[q].y), (float)t[(size_t)c[q].x * 47 + li], acc);
    }
    for (; j < e; ++j) {
        int2 c = cn[j];
        acc = fmaf(__int_as_float(c.y), (float)t[(size_t)c.x * 47 + li], acc);
    }
    if (act) out[(size_t)w * 47 + lane] = acc;
}

// ---------------------------------------------------------------------------
extern "C" void kernel_launch(void* const* d_in, const int* in_sizes, int n_in,
                              void* d_out, int out_size, void* d_ws, size_t ws_size,
                              hipStream_t stream) {
    const float* x  = (const float*)d_in[0];
    const void*  ei = d_in[1];
    // d_in[2] = edge_attr, unused by the reference forward
    const float* W1 = (const float*)d_in[3];
    const float* b1 = (const float*)d_in[4];
    const float* W2 = (const float*)d_in[5];
    const float* b2 = (const float*)d_in[6];
    const float* W3 = (const float*)d_in[7];
    const float* b3 = (const float*)d_in[8];
    float* out = (float*)d_out;

    size_t off = 0;
    auto alloc = [&](size_t bytes) -> void* {
        void* p = (char*)d_ws + off;
        off += (bytes + 511) & ~(size_t)511;
        return p;
    };
    float*  dis     = (float*)alloc((size_t)N_NODES * 4);
    int*    deg     = (int*)  alloc((size_t)N_NODES * 4);
    int*    rowst   = (int*)  alloc((size_t)N_NODES * 4);
    int*    cursor  = (int*)  alloc((size_t)N_NODES * 4);
    int*    bsum    = (int*)  alloc(128 * 4);
    int*    boff    = (int*)  alloc(128 * 4);
    int*    flag    = (int*)  alloc(64);
    int2*   csr_cn  = (int2*) alloc((size_t)N_EDGES * 8);
    __half* tbuf    = (__half*)alloc((size_t)N_NODES * 128 * 2);  // fp16 t rows
    float*  hbuf    = (float*) alloc((size_t)N_NODES * 128 * 4);  // fp32 activations
    (void)ws_size; (void)in_sizes; (void)n_in; (void)out_size;

    // --- graph preprocessing (per launch; ws is re-poisoned each call) ---
    detect_i64<<<1, 256, 0, stream>>>((const int*)ei, flag);
    zero_i32<<<(N_NODES + 255) / 256, 256, 0, stream>>>(deg, N_NODES);
    count_deg<<<N_EDGES / 256, 256, 0, stream>>>(ei, flag, deg);
    compute_dis<<<(N_NODES + 255) / 256, 256, 0, stream>>>(deg, dis);
    int nb = (N_NODES + 1023) / 1024;   // 98
    scan_bsum<<<nb, 256, 0, stream>>>(deg, bsum);
    scan_boff<<<1, 128, 0, stream>>>(bsum, boff, nb);
    scan_write<<<nb, 256, 0, stream>>>(deg, boff, rowst, cursor);
    fill_csr<<<N_EDGES / 256, 256, 0, stream>>>(ei, flag, dis, cursor, csr_cn);

    // --- layer 1: t = x@W1 (fp16) ; h = relu(agg) (fp32) ---
    dim3 g128((N_NODES + 63) / 64, 2);
    gemm_tile<__half, 64, 256><<<g128, 256, 0, stream>>>(x, W1, tbuf, 128);
    agg_c128<<<(N_NODES + 3) / 4, 256, 0, stream>>>(tbuf, rowst, deg, csr_cn, dis, b1, hbuf, 1);
    // --- layer 2 ---
    gemm_tile<__half, 64, 256><<<g128, 256, 0, stream>>>(hbuf, W2, tbuf, 128);
    agg_c128<<<(N_NODES + 3) / 4, 256, 0, stream>>>(tbuf, rowst, deg, csr_cn, dis, b2, hbuf, 1);
    // --- layer 3 (47 cols, no relu) ---
    dim3 g47((N_NODES + 63) / 64, 1);
    gemm_tile<__half, 48, 192><<<g47, 192, 0, stream>>>(hbuf, W3, tbuf, 47);
    agg_c47<<<(N_NODES + 3) / 4, 256, 0, stream>>>(tbuf, rowst, deg, csr_cn, dis, b3, out);
}

// Round 4
// 644.193 us; speedup vs baseline: 1.6587x; 1.1759x over previous
//
#include <hip/hip_runtime.h>
#include <hip/hip_fp16.h>
#include <cstdint>
#include <cstddef>

#define N_NODES 100000
#define N_EDGES 1600000

typedef _Float16 half8 __attribute__((ext_vector_type(8)));
typedef float floatx4 __attribute__((ext_vector_type(4)));

// ---------------------------------------------------------------------------
// edge_index dtype handling: JAX requests int64 but (with x64 disabled) may
// deliver int32. Detect on-device: for int64, the high 32-bit word of every
// element is 0 (values in [0,1e5)); for int32, odd words are random values.
// ---------------------------------------------------------------------------
static __device__ __forceinline__ int edge_row(const void* ei, int i64, int e) {
    return i64 ? (int)((const long long*)ei)[e] : ((const int*)ei)[e];
}
static __device__ __forceinline__ int edge_col(const void* ei, int i64, int e) {
    return i64 ? (int)((const long long*)ei)[N_EDGES + e] : ((const int*)ei)[N_EDGES + e];
}

__global__ void detect_i64(const int* __restrict__ w, int* __restrict__ flag) {
    __shared__ int red[256];
    int acc = 0;
    for (int j = threadIdx.x; j < 2048; j += 256) {
        int k = j * 781;             // max 1,598,707 < 1.6M
        acc |= w[2 * k + 1];
    }
    red[threadIdx.x] = acc;
    __syncthreads();
    for (int off = 128; off > 0; off >>= 1) {
        if (threadIdx.x < off) red[threadIdx.x] |= red[threadIdx.x + off];
        __syncthreads();
    }
    if (threadIdx.x == 0) *flag = (red[0] == 0) ? 1 : 0;
}

// ---------------------------------------------------------------------------
// degree / normalization
// ---------------------------------------------------------------------------
__global__ void zero_i32(int* __restrict__ p, int n) {
    int i = blockIdx.x * blockDim.x + threadIdx.x;
    if (i < n) p[i] = 0;
}

__global__ void count_deg(const void* __restrict__ ei, const int* __restrict__ flag,
                          int* __restrict__ deg) {
    int e = blockIdx.x * blockDim.x + threadIdx.x;
    if (e >= N_EDGES) return;
    int r = edge_row(ei, *flag, e);
    atomicAdd(&deg[r], 1);
}

__global__ void compute_dis(const int* __restrict__ deg, float* __restrict__ dis) {
    int i = blockIdx.x * blockDim.x + threadIdx.x;
    if (i < N_NODES) dis[i] = rsqrtf((float)deg[i] + 1.0f);
}

// ---------------------------------------------------------------------------
// exclusive scan of deg -> row_start (3-kernel, 1024 elems/block)
// ---------------------------------------------------------------------------
__global__ void scan_bsum(const int* __restrict__ deg, int* __restrict__ bsum) {
    __shared__ int sd[256];
    int base = blockIdx.x * 1024;
    int t = threadIdx.x;
    int s = 0;
    for (int j = 0; j < 4; ++j) {
        int idx = base + t + j * 256;
        if (idx < N_NODES) s += deg[idx];
    }
    sd[t] = s;
    __syncthreads();
    for (int off = 128; off > 0; off >>= 1) {
        if (t < off) sd[t] += sd[t + off];
        __syncthreads();
    }
    if (t == 0) bsum[blockIdx.x] = sd[0];
}

__global__ void scan_boff(const int* __restrict__ bsum, int* __restrict__ boff, int nb) {
    __shared__ int sd[128];
    int t = threadIdx.x;
    int v = (t < nb) ? bsum[t] : 0;
    sd[t] = v;
    __syncthreads();
    for (int off = 1; off < 128; off <<= 1) {
        int add = (t >= off) ? sd[t - off] : 0;
        __syncthreads();
        sd[t] += add;
        __syncthreads();
    }
    if (t < nb) boff[t] = sd[t] - v;   // exclusive
}

__global__ void scan_write(const int* __restrict__ deg, const int* __restrict__ boff,
                           int* __restrict__ rowst, int* __restrict__ cursor) {
    __shared__ int ts[256];
    int t = threadIdx.x;
    int base = blockIdx.x * 1024 + t * 4;
    int v[4];
    int s = 0;
    for (int j = 0; j < 4; ++j) {
        int idx = base + j;
        v[j] = (idx < N_NODES) ? deg[idx] : 0;
        s += v[j];
    }
    ts[t] = s;
    __syncthreads();
    int self = s;
    for (int off = 1; off < 256; off <<= 1) {
        int add = (t >= off) ? ts[t - off] : 0;
        __syncthreads();
        ts[t] += add;
        __syncthreads();
    }
    int run = boff[blockIdx.x] + ts[t] - self;
    for (int j = 0; j < 4; ++j) {
        int idx = base + j;
        if (idx < N_NODES) { rowst[idx] = run; cursor[idx] = run; }
        run += v[j];
    }
}

// packed CSR entry: .x = col, .y = norm (bit-cast float)
__global__ void fill_csr(const void* __restrict__ ei, const int* __restrict__ flag,
                         const float* __restrict__ dis, int* __restrict__ cursor,
                         int2* __restrict__ csr_cn) {
    int e = blockIdx.x * blockDim.x + threadIdx.x;
    if (e >= N_EDGES) return;
    int f = *flag;
    int r = edge_row(ei, f, e);
    int c = edge_col(ei, f, e);
    int pos = atomicAdd(&cursor[r], 1);
    csr_cn[pos] = make_int2(c, __float_as_int(dis[r] * dis[c]));
}

// ---------------------------------------------------------------------------
// MFMA GEMM: out[N x Mfull](fp16) = in[N x 128](fp32) @ W[128 x Mfull](fp32),
// via mfma_f32_16x16x32_f16, fp32 accumulation.
// - W staged once per block into LDS transposed+fp16: Wt[n][k], row stride
//   136 halfs (272 B) so B-fragment b128 reads are 2-way-bank (free).
// - A fragments loaded directly from global (lane m=lane&15, k=quad*8+j ->
//   8 consecutive floats = 2x float4), converted in-register to fp16.
// - Each wave: 16 rows x NT*16 cols, 4 k-steps. C/D: col=lane&15,
//   row=quad*4+reg.
// ---------------------------------------------------------------------------
template<int NT>   // number of 16-col tiles: 8 for M=128, 3 for M=47 (padded)
__global__ void __launch_bounds__(256)
gemm_mfma(const float* __restrict__ in, const float* __restrict__ W,
          __half* __restrict__ out, int Mfull) {
    constexpr int LDK = 136;                 // padded k-stride (halfs)
    constexpr int NCOL = NT * 16;
    __shared__ _Float16 Wt[NCOL * LDK];

    const int tid = threadIdx.x;
    // stage W[k][n] -> Wt[n][k] (fp16), coalesced global reads
    for (int idx = tid; idx < 128 * NCOL; idx += 256) {
        int k = idx / NCOL, n = idx % NCOL;
        float v = (n < Mfull) ? W[k * Mfull + n] : 0.0f;
        Wt[n * LDK + k] = (_Float16)v;
    }
    __syncthreads();

    const int wave = tid >> 6, lane = tid & 63;
    const int quad = lane >> 4, m = lane & 15;
    const int rowbase = blockIdx.x * 64 + wave * 16;
    const int arow_i = rowbase + m;
    const bool avalid = arow_i < N_NODES;
    const float* arow = in + (size_t)(avalid ? arow_i : 0) * 128;

    // A fragments for all 4 k-tiles
    half8 a[4];
    #pragma unroll
    for (int kt = 0; kt < 4; ++kt) {
        const float4* p = (const float4*)(arow + kt * 32 + quad * 8);
        float4 f0 = p[0];
        float4 f1 = p[1];
        a[kt][0] = (_Float16)f0.x; a[kt][1] = (_Float16)f0.y;
        a[kt][2] = (_Float16)f0.z; a[kt][3] = (_Float16)f0.w;
        a[kt][4] = (_Float16)f1.x; a[kt][5] = (_Float16)f1.y;
        a[kt][6] = (_Float16)f1.z; a[kt][7] = (_Float16)f1.w;
    }

    floatx4 acc[NT];
    #pragma unroll
    for (int ct = 0; ct < NT; ++ct) acc[ct] = (floatx4){0.f, 0.f, 0.f, 0.f};

    #pragma unroll
    for (int ct = 0; ct < NT; ++ct) {
        #pragma unroll
        for (int kt = 0; kt < 4; ++kt) {
            half8 b = *(const half8*)&Wt[(ct * 16 + m) * LDK + kt * 32 + quad * 8];
            acc[ct] = __builtin_amdgcn_mfma_f32_16x16x32_f16(a[kt], b, acc[ct], 0, 0, 0);
        }
    }

    const int rs0 = rowbase + quad * 4;
    #pragma unroll
    for (int ct = 0; ct < NT; ++ct) {
        int col = ct * 16 + m;
        if (col >= Mfull) continue;
        #pragma unroll
        for (int r = 0; r < 4; ++r) {
            int rs = rs0 + r;
            if (rs < N_NODES)
                out[(size_t)rs * Mfull + col] = __float2half(acc[ct][r]);
        }
    }
}

// ---------------------------------------------------------------------------
// CSR aggregation over fp16 t rows, software-pipelined 6-wide.
// out[i] = sum_e nrm_e * t[col_e] + dis_i^2 * t[i] + bias  (optional relu)
// ---------------------------------------------------------------------------
#define AGG_DEPTH 6

__global__ void agg_c128(const __half* __restrict__ t, const int* __restrict__ rowst,
                         const int* __restrict__ deg, const int2* __restrict__ cn,
                         const float* __restrict__ dis, const float* __restrict__ bias,
                         float* __restrict__ out, int relu) {
    int w = blockIdx.x * (blockDim.x >> 6) + (threadIdx.x >> 6);
    int lane = threadIdx.x & 63;
    if (w >= N_NODES) return;
    int s = rowst[w], d = deg[w];
    float di = dis[w];
    float sn = di * di;
    float2 tv = __half22float2(((const __half2*)(t + (size_t)w * 128))[lane]);
    float2 bv = ((const float2*)bias)[lane];
    float ax = fmaf(sn, tv.x, bv.x);
    float ay = fmaf(sn, tv.y, bv.y);
    int e = s + d;
    int j = s;
    if (j + AGG_DEPTH <= e) {
        int2 c[AGG_DEPTH];
        #pragma unroll
        for (int q = 0; q < AGG_DEPTH; ++q) c[q] = cn[j + q];
        j += AGG_DEPTH;
        while (j + AGG_DEPTH <= e) {
            int2 n[AGG_DEPTH];
            #pragma unroll
            for (int q = 0; q < AGG_DEPTH; ++q) n[q] = cn[j + q];
            __half2 v[AGG_DEPTH];
            #pragma unroll
            for (int q = 0; q < AGG_DEPTH; ++q)
                v[q] = ((const __half2*)(t + (size_t)c[q].x * 128))[lane];
            #pragma unroll
            for (int q = 0; q < AGG_DEPTH; ++q) {
                float2 f = __half22float2(v[q]);
                float nw = __int_as_float(c[q].y);
                ax = fmaf(nw, f.x, ax);
                ay = fmaf(nw, f.y, ay);
            }
            #pragma unroll
            for (int q = 0; q < AGG_DEPTH; ++q) c[q] = n[q];
            j += AGG_DEPTH;
        }
        #pragma unroll
        for (int q = 0; q < AGG_DEPTH; ++q) {
            __half2 vv = ((const __half2*)(t + (size_t)c[q].x * 128))[lane];
            float2 f = __half22float2(vv);
            float nw = __int_as_float(c[q].y);
            ax = fmaf(nw, f.x, ax);
            ay = fmaf(nw, f.y, ay);
        }
    }
    for (; j < e; ++j) {
        int2 c = cn[j];
        float2 f = __half22float2(((const __half2*)(t + (size_t)c.x * 128))[lane]);
        float nw = __int_as_float(c.y);
        ax = fmaf(nw, f.x, ax);
        ay = fmaf(nw, f.y, ay);
    }
    if (relu) { ax = fmaxf(ax, 0.f); ay = fmaxf(ay, 0.f); }
    ((float2*)(out + (size_t)w * 128))[lane] = make_float2(ax, ay);
}

__global__ void agg_c47(const __half* __restrict__ t, const int* __restrict__ rowst,
                        const int* __restrict__ deg, const int2* __restrict__ cn,
                        const float* __restrict__ dis, const float* __restrict__ bias,
                        float* __restrict__ out) {
    int w = blockIdx.x * (blockDim.x >> 6) + (threadIdx.x >> 6);
    int lane = threadIdx.x & 63;
    if (w >= N_NODES) return;
    int s = rowst[w], d = deg[w];
    float di = dis[w];
    float sn = di * di;
    bool act = lane < 47;
    int li = act ? lane : 0;
    float acc = act ? fmaf(sn, (float)t[(size_t)w * 47 + li], bias[li]) : 0.f;
    int e = s + d;
    int j = s;
    if (j + AGG_DEPTH <= e) {
        int2 c[AGG_DEPTH];
        #pragma unroll
        for (int q = 0; q < AGG_DEPTH; ++q) c[q] = cn[j + q];
        j += AGG_DEPTH;
        while (j + AGG_DEPTH <= e) {
            int2 n[AGG_DEPTH];
            #pragma unroll
            for (int q = 0; q < AGG_DEPTH; ++q) n[q] = cn[j + q];
            __half v[AGG_DEPTH];
            #pragma unroll
            for (int q = 0; q < AGG_DEPTH; ++q)
                v[q] = t[(size_t)c[q].x * 47 + li];
            #pragma unroll
            for (int q = 0; q < AGG_DEPTH; ++q)
                acc = fmaf(__int_as_float(c[q].y), (float)v[q], acc);
            #pragma unroll
            for (int q = 0; q < AGG_DEPTH; ++q) c[q] = n[q];
            j += AGG_DEPTH;
        }
        #pragma unroll
        for (int q = 0; q < AGG_DEPTH; ++q)
            acc = fmaf(__int_as_float(c[q].y), (float)t[(size_t)c[q].x * 47 + li], acc);
    }
    for (; j < e; ++j) {
        int2 c = cn[j];
        acc = fmaf(__int_as_float(c.y), (float)t[(size_t)c.x * 47 + li], acc);
    }
    if (act) out[(size_t)w * 47 + lane] = acc;
}

// ---------------------------------------------------------------------------
extern "C" void kernel_launch(void* const* d_in, const int* in_sizes, int n_in,
                              void* d_out, int out_size, void* d_ws, size_t ws_size,
                              hipStream_t stream) {
    const float* x  = (const float*)d_in[0];
    const void*  ei = d_in[1];
    // d_in[2] = edge_attr, unused by the reference forward
    const float* W1 = (const float*)d_in[3];
    const float* b1 = (const float*)d_in[4];
    const float* W2 = (const float*)d_in[5];
    const float* b2 = (const float*)d_in[6];
    const float* W3 = (const float*)d_in[7];
    const float* b3 = (const float*)d_in[8];
    float* out = (float*)d_out;

    size_t off = 0;
    auto alloc = [&](size_t bytes) -> void* {
        void* p = (char*)d_ws + off;
        off += (bytes + 511) & ~(size_t)511;
        return p;
    };
    float*  dis     = (float*)alloc((size_t)N_NODES * 4);
    int*    deg     = (int*)  alloc((size_t)N_NODES * 4);
    int*    rowst   = (int*)  alloc((size_t)N_NODES * 4);
    int*    cursor  = (int*)  alloc((size_t)N_NODES * 4);
    int*    bsum    = (int*)  alloc(128 * 4);
    int*    boff    = (int*)  alloc(128 * 4);
    int*    flag    = (int*)  alloc(64);
    int2*   csr_cn  = (int2*) alloc((size_t)N_EDGES * 8);
    __half* tbuf    = (__half*)alloc((size_t)N_NODES * 128 * 2);  // fp16 t rows
    float*  hbuf    = (float*) alloc((size_t)N_NODES * 128 * 4);  // fp32 activations
    (void)ws_size; (void)in_sizes; (void)n_in; (void)out_size;

    // --- graph preprocessing (per launch; ws is re-poisoned each call) ---
    detect_i64<<<1, 256, 0, stream>>>((const int*)ei, flag);
    zero_i32<<<(N_NODES + 255) / 256, 256, 0, stream>>>(deg, N_NODES);
    count_deg<<<N_EDGES / 256, 256, 0, stream>>>(ei, flag, deg);
    compute_dis<<<(N_NODES + 255) / 256, 256, 0, stream>>>(deg, dis);
    int nb = (N_NODES + 1023) / 1024;   // 98
    scan_bsum<<<nb, 256, 0, stream>>>(deg, bsum);
    scan_boff<<<1, 128, 0, stream>>>(bsum, boff, nb);
    scan_write<<<nb, 256, 0, stream>>>(deg, boff, rowst, cursor);
    fill_csr<<<N_EDGES / 256, 256, 0, stream>>>(ei, flag, dis, cursor, csr_cn);

    int gblocks = (N_NODES + 63) / 64;   // 1563

    // --- layer 1: t = x@W1 (fp16, MFMA) ; h = relu(agg) (fp32) ---
    gemm_mfma<8><<<gblocks, 256, 0, stream>>>(x, W1, tbuf, 128);
    agg_c128<<<(N_NODES + 3) / 4, 256, 0, stream>>>(tbuf, rowst, deg, csr_cn, dis, b1, hbuf, 1);
    // --- layer 2 ---
    gemm_mfma<8><<<gblocks, 256, 0, stream>>>(hbuf, W2, tbuf, 128);
    agg_c128<<<(N_NODES + 3) / 4, 256, 0, stream>>>(tbuf, rowst, deg, csr_cn, dis, b2, hbuf, 1);
    // --- layer 3 (47 cols, no relu) ---
    gemm_mfma<3><<<gblocks, 256, 0, stream>>>(hbuf, W3, tbuf, 47);
    agg_c47<<<(N_NODES + 3) / 4, 256, 0, stream>>>(tbuf, rowst, deg, csr_cn, dis, b3, out);
}

// Round 5
// 641.456 us; speedup vs baseline: 1.6658x; 1.0043x over previous
//
#include <hip/hip_runtime.h>
#include <hip/hip_fp16.h>
#include <cstdint>
#include <cstddef>

#define N_NODES 100000
#define N_EDGES 1600000
#define BSHIFT 9
#define NB ((N_NODES + (1 << BSHIFT) - 1) >> BSHIFT)   // 196 buckets
#define PTILE 4096

typedef _Float16 half8 __attribute__((ext_vector_type(8)));
typedef float floatx4 __attribute__((ext_vector_type(4)));

// ---------------------------------------------------------------------------
// edge_index dtype handling: JAX requests int64 but (with x64 disabled) may
// deliver int32. Detect on-device: for int64, the high 32-bit word of every
// element is 0 (values in [0,1e5)); for int32, odd words are random values.
// ---------------------------------------------------------------------------
static __device__ __forceinline__ int edge_row(const void* ei, int i64, int e) {
    return i64 ? (int)((const long long*)ei)[e] : ((const int*)ei)[e];
}
static __device__ __forceinline__ int edge_col(const void* ei, int i64, int e) {
    return i64 ? (int)((const long long*)ei)[N_EDGES + e] : ((const int*)ei)[N_EDGES + e];
}

__global__ void detect_i64(const int* __restrict__ w, int* __restrict__ flag) {
    __shared__ int red[256];
    int acc = 0;
    for (int j = threadIdx.x; j < 2048; j += 256) {
        int k = j * 781;             // max 1,598,707 < 1.6M
        acc |= w[2 * k + 1];
    }
    red[threadIdx.x] = acc;
    __syncthreads();
    for (int off = 128; off > 0; off >>= 1) {
        if (threadIdx.x < off) red[threadIdx.x] |= red[threadIdx.x + off];
        __syncthreads();
    }
    if (threadIdx.x == 0) *flag = (red[0] == 0) ? 1 : 0;
}

// ---------------------------------------------------------------------------
// degree / normalization
// ---------------------------------------------------------------------------
__global__ void zero_i32(int* __restrict__ p, int n) {
    int i = blockIdx.x * blockDim.x + threadIdx.x;
    if (i < n) p[i] = 0;
}

__global__ void count_deg(const void* __restrict__ ei, const int* __restrict__ flag,
                          int* __restrict__ deg) {
    int e = blockIdx.x * blockDim.x + threadIdx.x;
    if (e >= N_EDGES) return;
    int r = edge_row(ei, *flag, e);
    atomicAdd(&deg[r], 1);
}

__global__ void compute_dis(const int* __restrict__ deg, float* __restrict__ dis) {
    int i = blockIdx.x * blockDim.x + threadIdx.x;
    if (i < N_NODES) dis[i] = rsqrtf((float)deg[i] + 1.0f);
}

// ---------------------------------------------------------------------------
// exclusive scan of deg -> row_start (3-kernel, 1024 elems/block)
// ---------------------------------------------------------------------------
__global__ void scan_bsum(const int* __restrict__ deg, int* __restrict__ bsum) {
    __shared__ int sd[256];
    int base = blockIdx.x * 1024;
    int t = threadIdx.x;
    int s = 0;
    for (int j = 0; j < 4; ++j) {
        int idx = base + t + j * 256;
        if (idx < N_NODES) s += deg[idx];
    }
    sd[t] = s;
    __syncthreads();
    for (int off = 128; off > 0; off >>= 1) {
        if (t < off) sd[t] += sd[t + off];
        __syncthreads();
    }
    if (t == 0) bsum[blockIdx.x] = sd[0];
}

__global__ void scan_boff(const int* __restrict__ bsum, int* __restrict__ boff, int nb) {
    __shared__ int sd[128];
    int t = threadIdx.x;
    int v = (t < nb) ? bsum[t] : 0;
    sd[t] = v;
    __syncthreads();
    for (int off = 1; off < 128; off <<= 1) {
        int add = (t >= off) ? sd[t - off] : 0;
        __syncthreads();
        sd[t] += add;
        __syncthreads();
    }
    if (t < nb) boff[t] = sd[t] - v;   // exclusive
}

__global__ void scan_write(const int* __restrict__ deg, const int* __restrict__ boff,
                           int* __restrict__ rowst, int* __restrict__ cursor) {
    __shared__ int ts[256];
    int t = threadIdx.x;
    int base = blockIdx.x * 1024 + t * 4;
    int v[4];
    int s = 0;
    for (int j = 0; j < 4; ++j) {
        int idx = base + j;
        v[j] = (idx < N_NODES) ? deg[idx] : 0;
        s += v[j];
    }
    ts[t] = s;
    __syncthreads();
    int self = s;
    for (int off = 1; off < 256; off <<= 1) {
        int add = (t >= off) ? ts[t - off] : 0;
        __syncthreads();
        ts[t] += add;
        __syncthreads();
    }
    int run = boff[blockIdx.x] + ts[t] - self;
    for (int j = 0; j < 4; ++j) {
        int idx = base + j;
        if (idx < N_NODES) { rowst[idx] = run; cursor[idx] = run; }
        run += v[j];
    }
}

// bucket cursors start at the CSR offset of the bucket's first row
__global__ void init_bcur(const int* __restrict__ rowst, int* __restrict__ bcur) {
    int t = threadIdx.x;
    if (t < NB) bcur[t] = rowst[t << BSHIFT];
}

// ---------------------------------------------------------------------------
// Phase B: partition edges into row-range buckets with coalesced writes.
// One block per tile of 4096 edges. LDS histogram -> scan -> per-bucket global
// reservation -> LDS reorder -> coalesced flush to planar bucket arrays.
// ---------------------------------------------------------------------------
__global__ void __launch_bounds__(256)
partition_edges(const void* __restrict__ ei, const int* __restrict__ flag,
                const float* __restrict__ dis, int* __restrict__ bcur,
                int* __restrict__ bktRow, int* __restrict__ bktCol,
                float* __restrict__ bktNrm) {
    __shared__ int rows[PTILE];
    __shared__ int cols[PTILE];
    __shared__ float nrms[PTILE];
    __shared__ int h[256], sc[256], exs[256], base_s[256], p[256];

    const int tid = threadIdx.x;
    const int tbase = blockIdx.x * PTILE;
    const int tot = min(PTILE, N_EDGES - tbase);
    const int f = *flag;

    h[tid] = 0;
    p[tid] = 0;
    __syncthreads();

    // pass 1: histogram
    #pragma unroll
    for (int j = 0; j < PTILE / 256; ++j) {
        int idx = tbase + tid + j * 256;
        if (idx < N_EDGES) {
            int r = edge_row(ei, f, idx);
            atomicAdd(&h[r >> BSHIFT], 1);
        }
    }
    __syncthreads();

    // inclusive scan of h -> sc
    sc[tid] = h[tid];
    __syncthreads();
    for (int off = 1; off < 256; off <<= 1) {
        int v = (tid >= off) ? sc[tid - off] : 0;
        __syncthreads();
        sc[tid] += v;
        __syncthreads();
    }
    exs[tid] = sc[tid] - h[tid];   // exclusive
    if (tid < NB && h[tid] > 0) base_s[tid] = atomicAdd(&bcur[tid], h[tid]);
    __syncthreads();

    // pass 2: place into LDS, bucket-sorted
    #pragma unroll
    for (int j = 0; j < PTILE / 256; ++j) {
        int idx = tbase + tid + j * 256;
        if (idx < N_EDGES) {
            int r = edge_row(ei, f, idx);
            int c = edge_col(ei, f, idx);
            int b = r >> BSHIFT;
            int lp = atomicAdd(&p[b], 1);
            int slot = exs[b] + lp;
            rows[slot] = r;
            cols[slot] = c;
            nrms[slot] = dis[r] * dis[c];
        }
    }
    __syncthreads();

    // flush: coalesced planar writes; runs per bucket are contiguous
    for (int slot = tid; slot < tot; slot += 256) {
        int r = rows[slot];
        int b = r >> BSHIFT;
        int addr = base_s[b] + (slot - exs[b]);
        bktRow[addr] = r;
        bktCol[addr] = cols[slot];
        bktNrm[addr] = nrms[slot];
    }
}

// ---------------------------------------------------------------------------
// Phase C: one block per bucket; scatter records to final CSR slots. Write
// window is ~64 KB and single-writer (one block = one XCD L2) -> no write amp.
// ---------------------------------------------------------------------------
__global__ void __launch_bounds__(512)
scatter_bucket(const int* __restrict__ bktRow, const int* __restrict__ bktCol,
               const float* __restrict__ bktNrm, const int* __restrict__ rowst,
               int* __restrict__ cursor, int2* __restrict__ csr_cn) {
    int b = blockIdx.x;
    int start = rowst[b << BSHIFT];
    int end = (b == NB - 1) ? N_EDGES : rowst[(b + 1) << BSHIFT];
    for (int i = start + threadIdx.x; i < end; i += 512) {
        int r = bktRow[i];
        int pos = atomicAdd(&cursor[r], 1);
        csr_cn[pos] = make_int2(bktCol[i], __float_as_int(bktNrm[i]));
    }
}

// ---------------------------------------------------------------------------
// MFMA GEMM: out[N x Mfull](fp16) = in[N x 128](fp32) @ W[128 x Mfull](fp32),
// via mfma_f32_16x16x32_f16, fp32 accumulation.
// ---------------------------------------------------------------------------
template<int NT>   // number of 16-col tiles: 8 for M=128, 3 for M=47 (padded)
__global__ void __launch_bounds__(256)
gemm_mfma(const float* __restrict__ in, const float* __restrict__ W,
          __half* __restrict__ out, int Mfull) {
    constexpr int LDK = 136;                 // padded k-stride (halfs)
    constexpr int NCOL = NT * 16;
    __shared__ _Float16 Wt[NCOL * LDK];

    const int tid = threadIdx.x;
    for (int idx = tid; idx < 128 * NCOL; idx += 256) {
        int k = idx / NCOL, n = idx % NCOL;
        float v = (n < Mfull) ? W[k * Mfull + n] : 0.0f;
        Wt[n * LDK + k] = (_Float16)v;
    }
    __syncthreads();

    const int wave = tid >> 6, lane = tid & 63;
    const int quad = lane >> 4, m = lane & 15;
    const int rowbase = blockIdx.x * 64 + wave * 16;
    const int arow_i = rowbase + m;
    const bool avalid = arow_i < N_NODES;
    const float* arow = in + (size_t)(avalid ? arow_i : 0) * 128;

    half8 a[4];
    #pragma unroll
    for (int kt = 0; kt < 4; ++kt) {
        const float4* ptr = (const float4*)(arow + kt * 32 + quad * 8);
        float4 f0 = ptr[0];
        float4 f1 = ptr[1];
        a[kt][0] = (_Float16)f0.x; a[kt][1] = (_Float16)f0.y;
        a[kt][2] = (_Float16)f0.z; a[kt][3] = (_Float16)f0.w;
        a[kt][4] = (_Float16)f1.x; a[kt][5] = (_Float16)f1.y;
        a[kt][6] = (_Float16)f1.z; a[kt][7] = (_Float16)f1.w;
    }

    floatx4 acc[NT];
    #pragma unroll
    for (int ct = 0; ct < NT; ++ct) acc[ct] = (floatx4){0.f, 0.f, 0.f, 0.f};

    #pragma unroll
    for (int ct = 0; ct < NT; ++ct) {
        #pragma unroll
        for (int kt = 0; kt < 4; ++kt) {
            half8 b = *(const half8*)&Wt[(ct * 16 + m) * LDK + kt * 32 + quad * 8];
            acc[ct] = __builtin_amdgcn_mfma_f32_16x16x32_f16(a[kt], b, acc[ct], 0, 0, 0);
        }
    }

    const int rs0 = rowbase + quad * 4;
    #pragma unroll
    for (int ct = 0; ct < NT; ++ct) {
        int col = ct * 16 + m;
        if (col >= Mfull) continue;
        #pragma unroll
        for (int r = 0; r < 4; ++r) {
            int rs = rs0 + r;
            if (rs < N_NODES)
                out[(size_t)rs * Mfull + col] = __float2half(acc[ct][r]);
        }
    }
}

// ---------------------------------------------------------------------------
// CSR aggregation over fp16 t rows, software-pipelined 6-wide.
// ---------------------------------------------------------------------------
#define AGG_DEPTH 6

__global__ void agg_c128(const __half* __restrict__ t, const int* __restrict__ rowst,
                         const int* __restrict__ deg, const int2* __restrict__ cn,
                         const float* __restrict__ dis, const float* __restrict__ bias,
                         float* __restrict__ out, int relu) {
    int w = blockIdx.x * (blockDim.x >> 6) + (threadIdx.x >> 6);
    int lane = threadIdx.x & 63;
    if (w >= N_NODES) return;
    int s = rowst[w], d = deg[w];
    float di = dis[w];
    float sn = di * di;
    float2 tv = __half22float2(((const __half2*)(t + (size_t)w * 128))[lane]);
    float2 bv = ((const float2*)bias)[lane];
    float ax = fmaf(sn, tv.x, bv.x);
    float ay = fmaf(sn, tv.y, bv.y);
    int e = s + d;
    int j = s;
    if (j + AGG_DEPTH <= e) {
        int2 c[AGG_DEPTH];
        #pragma unroll
        for (int q = 0; q < AGG_DEPTH; ++q) c[q] = cn[j + q];
        j += AGG_DEPTH;
        while (j + AGG_DEPTH <= e) {
            int2 n[AGG_DEPTH];
            #pragma unroll
            for (int q = 0; q < AGG_DEPTH; ++q) n[q] = cn[j + q];
            __half2 v[AGG_DEPTH];
            #pragma unroll
            for (int q = 0; q < AGG_DEPTH; ++q)
                v[q] = ((const __half2*)(t + (size_t)c[q].x * 128))[lane];
            #pragma unroll
            for (int q = 0; q < AGG_DEPTH; ++q) {
                float2 fv = __half22float2(v[q]);
                float nw = __int_as_float(c[q].y);
                ax = fmaf(nw, fv.x, ax);
                ay = fmaf(nw, fv.y, ay);
            }
            #pragma unroll
            for (int q = 0; q < AGG_DEPTH; ++q) c[q] = n[q];
            j += AGG_DEPTH;
        }
        #pragma unroll
        for (int q = 0; q < AGG_DEPTH; ++q) {
            __half2 vv = ((const __half2*)(t + (size_t)c[q].x * 128))[lane];
            float2 fv = __half22float2(vv);
            float nw = __int_as_float(c[q].y);
            ax = fmaf(nw, fv.x, ax);
            ay = fmaf(nw, fv.y, ay);
        }
    }
    for (; j < e; ++j) {
        int2 c = cn[j];
        float2 fv = __half22float2(((const __half2*)(t + (size_t)c.x * 128))[lane]);
        float nw = __int_as_float(c.y);
        ax = fmaf(nw, fv.x, ax);
        ay = fmaf(nw, fv.y, ay);
    }
    if (relu) { ax = fmaxf(ax, 0.f); ay = fmaxf(ay, 0.f); }
    ((float2*)(out + (size_t)w * 128))[lane] = make_float2(ax, ay);
}

__global__ void agg_c47(const __half* __restrict__ t, const int* __restrict__ rowst,
                        const int* __restrict__ deg, const int2* __restrict__ cn,
                        const float* __restrict__ dis, const float* __restrict__ bias,
                        float* __restrict__ out) {
    int w = blockIdx.x * (blockDim.x >> 6) + (threadIdx.x >> 6);
    int lane = threadIdx.x & 63;
    if (w >= N_NODES) return;
    int s = rowst[w], d = deg[w];
    float di = dis[w];
    float sn = di * di;
    bool act = lane < 47;
    int li = act ? lane : 0;
    float acc = act ? fmaf(sn, (float)t[(size_t)w * 47 + li], bias[li]) : 0.f;
    int e = s + d;
    int j = s;
    if (j + AGG_DEPTH <= e) {
        int2 c[AGG_DEPTH];
        #pragma unroll
        for (int q = 0; q < AGG_DEPTH; ++q) c[q] = cn[j + q];
        j += AGG_DEPTH;
        while (j + AGG_DEPTH <= e) {
            int2 n[AGG_DEPTH];
            #pragma unroll
            for (int q = 0; q < AGG_DEPTH; ++q) n[q] = cn[j + q];
            __half v[AGG_DEPTH];
            #pragma unroll
            for (int q = 0; q < AGG_DEPTH; ++q)
                v[q] = t[(size_t)c[q].x * 47 + li];
            #pragma unroll
            for (int q = 0; q < AGG_DEPTH; ++q)
                acc = fmaf(__int_as_float(c[q].y), (float)v[q], acc);
            #pragma unroll
            for (int q = 0; q < AGG_DEPTH; ++q) c[q] = n[q];
            j += AGG_DEPTH;
        }
        #pragma unroll
        for (int q = 0; q < AGG_DEPTH; ++q)
            acc = fmaf(__int_as_float(c[q].y), (float)t[(size_t)c[q].x * 47 + li], acc);
    }
    for (; j < e; ++j) {
        int2 c = cn[j];
        acc = fmaf(__int_as_float(c.y), (float)t[(size_t)c.x * 47 + li], acc);
    }
    if (act) out[(size_t)w * 47 + lane] = acc;
}

// ---------------------------------------------------------------------------
extern "C" void kernel_launch(void* const* d_in, const int* in_sizes, int n_in,
                              void* d_out, int out_size, void* d_ws, size_t ws_size,
                              hipStream_t stream) {
    const float* x  = (const float*)d_in[0];
    const void*  ei = d_in[1];
    // d_in[2] = edge_attr, unused by the reference forward
    const float* W1 = (const float*)d_in[3];
    const float* b1 = (const float*)d_in[4];
    const float* W2 = (const float*)d_in[5];
    const float* b2 = (const float*)d_in[6];
    const float* W3 = (const float*)d_in[7];
    const float* b3 = (const float*)d_in[8];
    float* out = (float*)d_out;

    size_t off = 0;
    auto alloc = [&](size_t bytes) -> void* {
        void* p = (char*)d_ws + off;
        off += (bytes + 511) & ~(size_t)511;
        return p;
    };
    float*  dis     = (float*)alloc((size_t)N_NODES * 4);
    int*    deg     = (int*)  alloc((size_t)N_NODES * 4);
    int*    rowst   = (int*)  alloc((size_t)N_NODES * 4);
    int*    cursor  = (int*)  alloc((size_t)N_NODES * 4);
    int*    bsum    = (int*)  alloc(128 * 4);
    int*    boff    = (int*)  alloc(128 * 4);
    int*    flag    = (int*)  alloc(64);
    int*    bcur    = (int*)  alloc(NB * 4);
    int2*   csr_cn  = (int2*) alloc((size_t)N_EDGES * 8);
    __half* tbuf    = (__half*)alloc((size_t)N_NODES * 128 * 2);  // fp16 t rows
    float*  hbuf    = (float*) alloc((size_t)N_NODES * 128 * 4);  // fp32 activations
    // bucket arrays alias hbuf (only live during preprocessing; 19.2MB < 51.2MB)
    int*    bktRow  = (int*)hbuf;
    int*    bktCol  = bktRow + N_EDGES;
    float*  bktNrm  = (float*)(bktCol + N_EDGES);
    (void)ws_size; (void)in_sizes; (void)n_in; (void)out_size;

    // --- graph preprocessing (per launch; ws is re-poisoned each call) ---
    detect_i64<<<1, 256, 0, stream>>>((const int*)ei, flag);
    zero_i32<<<(N_NODES + 255) / 256, 256, 0, stream>>>(deg, N_NODES);
    count_deg<<<N_EDGES / 256, 256, 0, stream>>>(ei, flag, deg);
    compute_dis<<<(N_NODES + 255) / 256, 256, 0, stream>>>(deg, dis);
    int nb = (N_NODES + 1023) / 1024;   // 98
    scan_bsum<<<nb, 256, 0, stream>>>(deg, bsum);
    scan_boff<<<1, 128, 0, stream>>>(bsum, boff, nb);
    scan_write<<<nb, 256, 0, stream>>>(deg, boff, rowst, cursor);
    init_bcur<<<1, 256, 0, stream>>>(rowst, bcur);
    partition_edges<<<(N_EDGES + PTILE - 1) / PTILE, 256, 0, stream>>>(
        ei, flag, dis, bcur, bktRow, bktCol, bktNrm);
    scatter_bucket<<<NB, 512, 0, stream>>>(bktRow, bktCol, bktNrm, rowst, cursor, csr_cn);

    int gblocks = (N_NODES + 63) / 64;   // 1563

    // --- layer 1: t = x@W1 (fp16, MFMA) ; h = relu(agg) (fp32) ---
    gemm_mfma<8><<<gblocks, 256, 0, stream>>>(x, W1, tbuf, 128);
    agg_c128<<<(N_NODES + 3) / 4, 256, 0, stream>>>(tbuf, rowst, deg, csr_cn, dis, b1, hbuf, 1);
    // --- layer 2 ---
    gemm_mfma<8><<<gblocks, 256, 0, stream>>>(hbuf, W2, tbuf, 128);
    agg_c128<<<(N_NODES + 3) / 4, 256, 0, stream>>>(tbuf, rowst, deg, csr_cn, dis, b2, hbuf, 1);
    // --- layer 3 (47 cols, no relu) ---
    gemm_mfma<3><<<gblocks, 256, 0, stream>>>(hbuf, W3, tbuf, 47);
    agg_c47<<<(N_NODES + 3) / 4, 256, 0, stream>>>(tbuf, rowst, deg, csr_cn, dis, b3, out);
}

// Round 6
// 510.368 us; speedup vs baseline: 2.0936x; 1.2568x over previous
//
#include <hip/hip_runtime.h>
#include <hip/hip_fp16.h>
#include <cstdint>
#include <cstddef>

#define N_NODES 100000
#define N_EDGES 1600000
#define BSHIFT 9
#define BSIZE (1 << BSHIFT)
#define NB ((N_NODES + BSIZE - 1) >> BSHIFT)   // 196 buckets
#define PTILE 4096

typedef _Float16 half8 __attribute__((ext_vector_type(8)));
typedef float floatx4 __attribute__((ext_vector_type(4)));

// ---------------------------------------------------------------------------
// edge_index dtype handling (int64 vs int32 delivered by JAX)
// ---------------------------------------------------------------------------
static __device__ __forceinline__ int edge_row(const void* ei, int i64, int e) {
    return i64 ? (int)((const long long*)ei)[e] : ((const int*)ei)[e];
}
static __device__ __forceinline__ int edge_col(const void* ei, int i64, int e) {
    return i64 ? (int)((const long long*)ei)[N_EDGES + e] : ((const int*)ei)[N_EDGES + e];
}

__global__ void detect_i64(const int* __restrict__ w, int* __restrict__ flag) {
    __shared__ int red[256];
    int acc = 0;
    for (int j = threadIdx.x; j < 2048; j += 256) {
        int k = j * 781;
        acc |= w[2 * k + 1];
    }
    red[threadIdx.x] = acc;
    __syncthreads();
    for (int off = 128; off > 0; off >>= 1) {
        if (threadIdx.x < off) red[threadIdx.x] |= red[threadIdx.x + off];
        __syncthreads();
    }
    if (threadIdx.x == 0) *flag = (red[0] == 0) ? 1 : 0;
}

// ---------------------------------------------------------------------------
// Preprocessing v2: no random global atomics anywhere.
// ---------------------------------------------------------------------------
__global__ void init_pre(int* __restrict__ bsize) {
    if (threadIdx.x < NB + 1) bsize[threadIdx.x] = 0;
}

// per-tile LDS histogram of buckets -> few global atomics (196/block)
__global__ void __launch_bounds__(256)
hist_buckets(const void* __restrict__ ei, const int* __restrict__ flag,
             int* __restrict__ bsize) {
    __shared__ int h[256];
    const int tid = threadIdx.x;
    const int tbase = blockIdx.x * PTILE;
    const int f = *flag;
    h[tid] = 0;
    __syncthreads();
    #pragma unroll
    for (int j = 0; j < PTILE / 256; ++j) {
        int idx = tbase + tid + j * 256;
        if (idx < N_EDGES) {
            int r = edge_row(ei, f, idx);
            atomicAdd(&h[r >> BSHIFT], 1);
        }
    }
    __syncthreads();
    if (tid < NB && h[tid] > 0) atomicAdd(&bsize[tid], h[tid]);
}

// exclusive scan of bucket sizes -> bbase[NB+1], bcur
__global__ void scan_buckets(const int* __restrict__ bsize, int* __restrict__ bbase,
                             int* __restrict__ bcur) {
    __shared__ int sd[256];
    int t = threadIdx.x;
    int v = (t < NB) ? bsize[t] : 0;
    sd[t] = v;
    __syncthreads();
    for (int off = 1; off < 256; off <<= 1) {
        int add = (t >= off) ? sd[t - off] : 0;
        __syncthreads();
        sd[t] += add;
        __syncthreads();
    }
    if (t < NB) {
        bbase[t] = sd[t] - v;
        bcur[t] = sd[t] - v;
    }
    if (t == 255) bbase[NB] = sd[255];   // == N_EDGES
}

// partition edges into buckets (rows+cols planar, coalesced flush)
__global__ void __launch_bounds__(256)
partition_edges(const void* __restrict__ ei, const int* __restrict__ flag,
                int* __restrict__ bcur, int* __restrict__ bktRow,
                int* __restrict__ bktCol) {
    __shared__ int rows[PTILE];
    __shared__ int cols[PTILE];
    __shared__ int h[256], sc[256], exs[256], base_s[256], p[256];

    const int tid = threadIdx.x;
    const int tbase = blockIdx.x * PTILE;
    const int tot = min(PTILE, N_EDGES - tbase);
    const int f = *flag;

    h[tid] = 0;
    p[tid] = 0;
    __syncthreads();

    #pragma unroll
    for (int j = 0; j < PTILE / 256; ++j) {
        int idx = tbase + tid + j * 256;
        if (idx < N_EDGES) {
            int r = edge_row(ei, f, idx);
            atomicAdd(&h[r >> BSHIFT], 1);
        }
    }
    __syncthreads();

    sc[tid] = h[tid];
    __syncthreads();
    for (int off = 1; off < 256; off <<= 1) {
        int v = (tid >= off) ? sc[tid - off] : 0;
        __syncthreads();
        sc[tid] += v;
        __syncthreads();
    }
    exs[tid] = sc[tid] - h[tid];
    if (tid < NB && h[tid] > 0) base_s[tid] = atomicAdd(&bcur[tid], h[tid]);
    __syncthreads();

    #pragma unroll
    for (int j = 0; j < PTILE / 256; ++j) {
        int idx = tbase + tid + j * 256;
        if (idx < N_EDGES) {
            int r = edge_row(ei, f, idx);
            int c = edge_col(ei, f, idx);
            int b = r >> BSHIFT;
            int lp = atomicAdd(&p[b], 1);
            int slot = exs[b] + lp;
            rows[slot] = r;
            cols[slot] = c;
        }
    }
    __syncthreads();

    for (int slot = tid; slot < tot; slot += 256) {
        int r = rows[slot];
        int b = r >> BSHIFT;
        int addr = base_s[b] + (slot - exs[b]);
        bktRow[addr] = r;
        bktCol[addr] = cols[slot];
    }
}

// per-bucket: degree histogram (LDS) + local scan -> deg, rowst (coalesced)
__global__ void __launch_bounds__(512)
bucket_stats(const int* __restrict__ bktRow, const int* __restrict__ bbase,
             int* __restrict__ deg, int* __restrict__ rowst) {
    __shared__ int cnt[512];
    __shared__ int sd[512];
    const int b = blockIdx.x;
    const int t = threadIdx.x;
    const int start = bbase[b], end = bbase[b + 1];
    cnt[t] = 0;
    __syncthreads();
    for (int i = start + t; i < end; i += 512)
        atomicAdd(&cnt[bktRow[i] - (b << BSHIFT)], 1);
    __syncthreads();
    int v = cnt[t];
    sd[t] = v;
    __syncthreads();
    for (int off = 1; off < 512; off <<= 1) {
        int add = (t >= off) ? sd[t - off] : 0;
        __syncthreads();
        sd[t] += add;
        __syncthreads();
    }
    int node = (b << BSHIFT) + t;
    if (node < N_NODES) {
        deg[node] = v;
        rowst[node] = start + sd[t] - v;
    }
}

__global__ void compute_dis(const int* __restrict__ deg, float* __restrict__ dis) {
    int i = blockIdx.x * blockDim.x + threadIdx.x;
    if (i < N_NODES) dis[i] = rsqrtf((float)deg[i] + 1.0f);
}

// per-bucket scatter to final CSR with LDS cursors; nrm computed here
__global__ void __launch_bounds__(512)
scatter_bucket(const int* __restrict__ bktRow, const int* __restrict__ bktCol,
               const int* __restrict__ bbase, const int* __restrict__ rowst,
               const float* __restrict__ dis, int2* __restrict__ csr_cn) {
    __shared__ int cur[512];
    __shared__ float dl[512];
    const int b = blockIdx.x;
    const int t = threadIdx.x;
    const int start = bbase[b], end = bbase[b + 1];
    int node = (b << BSHIFT) + t;
    cur[t] = (node < N_NODES) ? rowst[node] : 0;
    dl[t]  = (node < N_NODES) ? dis[node] : 0.f;
    __syncthreads();
    for (int i = start + t; i < end; i += 512) {
        int r = bktRow[i];
        int c = bktCol[i];
        int lr = r - (b << BSHIFT);
        int pos = atomicAdd(&cur[lr], 1);
        float nrm = dl[lr] * dis[c];
        csr_cn[pos] = make_int2(c, __float_as_int(nrm));
    }
}

// ---------------------------------------------------------------------------
// MFMA GEMM with XOR-swizzled LDS B tile (conflict-free b128 access).
// Physical layout: row n (=output col), 16 chunks of 8 halfs; logical chunk c
// stored at p = c ^ (n&7). Row stride exactly 128 halfs (256 B).
// TIn = float (layer 1) or _Float16 (layers 2,3).
// ---------------------------------------------------------------------------
template<typename TIn, int NT>
__global__ void __launch_bounds__(256)
gemm_mfma(const TIn* __restrict__ in, const float* __restrict__ W,
          __half* __restrict__ out, int Mfull) {
    constexpr int NCOL = NT * 16;
    __shared__ _Float16 Wt[NCOL * 128];

    const int tid = threadIdx.x;
    // stage: chunkIdx -> (n = chunkIdx % NCOL, c = chunkIdx / NCOL)
    for (int chunkIdx = tid; chunkIdx < NCOL * 16; chunkIdx += 256) {
        int n = chunkIdx % NCOL;
        int c = chunkIdx / NCOL;
        half8 v;
        #pragma unroll
        for (int i = 0; i < 8; ++i) {
            int k = c * 8 + i;
            v[i] = (n < Mfull) ? (_Float16)W[k * Mfull + n] : (_Float16)0.f;
        }
        *(half8*)&Wt[n * 128 + (c ^ (n & 7)) * 8] = v;
    }
    __syncthreads();

    const int wave = tid >> 6, lane = tid & 63;
    const int quad = lane >> 4, m = lane & 15;
    const int rowbase = blockIdx.x * 64 + wave * 16;
    const int arow_i = rowbase + m;
    const bool avalid = arow_i < N_NODES;
    const TIn* arow = in + (size_t)(avalid ? arow_i : 0) * 128;

    half8 a[4];
    #pragma unroll
    for (int kt = 0; kt < 4; ++kt) {
        if constexpr (sizeof(TIn) == 4) {
            const float4* ptr = (const float4*)((const float*)arow + kt * 32 + quad * 8);
            float4 f0 = ptr[0];
            float4 f1 = ptr[1];
            a[kt][0] = (_Float16)f0.x; a[kt][1] = (_Float16)f0.y;
            a[kt][2] = (_Float16)f0.z; a[kt][3] = (_Float16)f0.w;
            a[kt][4] = (_Float16)f1.x; a[kt][5] = (_Float16)f1.y;
            a[kt][6] = (_Float16)f1.z; a[kt][7] = (_Float16)f1.w;
        } else {
            a[kt] = *(const half8*)((const _Float16*)arow + kt * 32 + quad * 8);
        }
    }

    floatx4 acc[NT];
    #pragma unroll
    for (int ct = 0; ct < NT; ++ct) acc[ct] = (floatx4){0.f, 0.f, 0.f, 0.f};

    #pragma unroll
    for (int ct = 0; ct < NT; ++ct) {
        #pragma unroll
        for (int kt = 0; kt < 4; ++kt) {
            int n = ct * 16 + m;
            half8 bfrag = *(const half8*)&Wt[n * 128 + ((kt * 4 + quad) ^ (m & 7)) * 8];
            acc[ct] = __builtin_amdgcn_mfma_f32_16x16x32_f16(a[kt], bfrag, acc[ct], 0, 0, 0);
        }
    }

    const int rs0 = rowbase + quad * 4;
    #pragma unroll
    for (int ct = 0; ct < NT; ++ct) {
        int col = ct * 16 + m;
        if (col >= Mfull) continue;
        #pragma unroll
        for (int r = 0; r < 4; ++r) {
            int rs = rs0 + r;
            if (rs < N_NODES)
                out[(size_t)rs * Mfull + col] = __float2half(acc[ct][r]);
        }
    }
}

// ---------------------------------------------------------------------------
// CSR aggregation over fp16 t rows, pipelined 6-wide.
// c128 variant outputs fp16 (activations); c47 outputs fp32 (final).
// ---------------------------------------------------------------------------
#define AGG_DEPTH 6

__global__ void agg_c128(const __half* __restrict__ t, const int* __restrict__ rowst,
                         const int* __restrict__ deg, const int2* __restrict__ cn,
                         const float* __restrict__ dis, const float* __restrict__ bias,
                         __half* __restrict__ out, int relu) {
    int w = blockIdx.x * (blockDim.x >> 6) + (threadIdx.x >> 6);
    int lane = threadIdx.x & 63;
    if (w >= N_NODES) return;
    int s = rowst[w], d = deg[w];
    float di = dis[w];
    float sn = di * di;
    float2 tv = __half22float2(((const __half2*)(t + (size_t)w * 128))[lane]);
    float2 bv = ((const float2*)bias)[lane];
    float ax = fmaf(sn, tv.x, bv.x);
    float ay = fmaf(sn, tv.y, bv.y);
    int e = s + d;
    int j = s;
    if (j + AGG_DEPTH <= e) {
        int2 c[AGG_DEPTH];
        #pragma unroll
        for (int q = 0; q < AGG_DEPTH; ++q) c[q] = cn[j + q];
        j += AGG_DEPTH;
        while (j + AGG_DEPTH <= e) {
            int2 n[AGG_DEPTH];
            #pragma unroll
            for (int q = 0; q < AGG_DEPTH; ++q) n[q] = cn[j + q];
            __half2 v[AGG_DEPTH];
            #pragma unroll
            for (int q = 0; q < AGG_DEPTH; ++q)
                v[q] = ((const __half2*)(t + (size_t)c[q].x * 128))[lane];
            #pragma unroll
            for (int q = 0; q < AGG_DEPTH; ++q) {
                float2 fv = __half22float2(v[q]);
                float nw = __int_as_float(c[q].y);
                ax = fmaf(nw, fv.x, ax);
                ay = fmaf(nw, fv.y, ay);
            }
            #pragma unroll
            for (int q = 0; q < AGG_DEPTH; ++q) c[q] = n[q];
            j += AGG_DEPTH;
        }
        #pragma unroll
        for (int q = 0; q < AGG_DEPTH; ++q) {
            __half2 vv = ((const __half2*)(t + (size_t)c[q].x * 128))[lane];
            float2 fv = __half22float2(vv);
            float nw = __int_as_float(c[q].y);
            ax = fmaf(nw, fv.x, ax);
            ay = fmaf(nw, fv.y, ay);
        }
    }
    for (; j < e; ++j) {
        int2 c = cn[j];
        float2 fv = __half22float2(((const __half2*)(t + (size_t)c.x * 128))[lane]);
        float nw = __int_as_float(c.y);
        ax = fmaf(nw, fv.x, ax);
        ay = fmaf(nw, fv.y, ay);
    }
    if (relu) { ax = fmaxf(ax, 0.f); ay = fmaxf(ay, 0.f); }
    ((__half2*)(out + (size_t)w * 128))[lane] = __float22half2_rn(make_float2(ax, ay));
}

__global__ void agg_c47(const __half* __restrict__ t, const int* __restrict__ rowst,
                        const int* __restrict__ deg, const int2* __restrict__ cn,
                        const float* __restrict__ dis, const float* __restrict__ bias,
                        float* __restrict__ out) {
    int w = blockIdx.x * (blockDim.x >> 6) + (threadIdx.x >> 6);
    int lane = threadIdx.x & 63;
    if (w >= N_NODES) return;
    int s = rowst[w], d = deg[w];
    float di = dis[w];
    float sn = di * di;
    bool act = lane < 47;
    int li = act ? lane : 0;
    float acc = act ? fmaf(sn, (float)t[(size_t)w * 47 + li], bias[li]) : 0.f;
    int e = s + d;
    int j = s;
    if (j + AGG_DEPTH <= e) {
        int2 c[AGG_DEPTH];
        #pragma unroll
        for (int q = 0; q < AGG_DEPTH; ++q) c[q] = cn[j + q];
        j += AGG_DEPTH;
        while (j + AGG_DEPTH <= e) {
            int2 n[AGG_DEPTH];
            #pragma unroll
            for (int q = 0; q < AGG_DEPTH; ++q) n[q] = cn[j + q];
            __half v[AGG_DEPTH];
            #pragma unroll
            for (int q = 0; q < AGG_DEPTH; ++q)
                v[q] = t[(size_t)c[q].x * 47 + li];
            #pragma unroll
            for (int q = 0; q < AGG_DEPTH; ++q)
                acc = fmaf(__int_as_float(c[q].y), (float)v[q], acc);
            #pragma unroll
            for (int q = 0; q < AGG_DEPTH; ++q) c[q] = n[q];
            j += AGG_DEPTH;
        }
        #pragma unroll
        for (int q = 0; q < AGG_DEPTH; ++q)
            acc = fmaf(__int_as_float(c[q].y), (float)t[(size_t)c[q].x * 47 + li], acc);
    }
    for (; j < e; ++j) {
        int2 c = cn[j];
        acc = fmaf(__int_as_float(c.y), (float)t[(size_t)c.x * 47 + li], acc);
    }
    if (act) out[(size_t)w * 47 + lane] = acc;
}

// ---------------------------------------------------------------------------
extern "C" void kernel_launch(void* const* d_in, const int* in_sizes, int n_in,
                              void* d_out, int out_size, void* d_ws, size_t ws_size,
                              hipStream_t stream) {
    const float* x  = (const float*)d_in[0];
    const void*  ei = d_in[1];
    const float* W1 = (const float*)d_in[3];
    const float* b1 = (const float*)d_in[4];
    const float* W2 = (const float*)d_in[5];
    const float* b2 = (const float*)d_in[6];
    const float* W3 = (const float*)d_in[7];
    const float* b3 = (const float*)d_in[8];
    float* out = (float*)d_out;

    size_t off = 0;
    auto alloc = [&](size_t bytes) -> void* {
        void* p = (char*)d_ws + off;
        off += (bytes + 511) & ~(size_t)511;
        return p;
    };
    float*  dis     = (float*)alloc((size_t)N_NODES * 4);
    int*    deg     = (int*)  alloc((size_t)N_NODES * 4);
    int*    rowst   = (int*)  alloc((size_t)N_NODES * 4);
    int*    bsize   = (int*)  alloc((NB + 1) * 4);
    int*    bbase   = (int*)  alloc((NB + 1) * 4);
    int*    bcur    = (int*)  alloc(NB * 4);
    int*    flag    = (int*)  alloc(64);
    int2*   csr_cn  = (int2*) alloc((size_t)N_EDGES * 8);
    __half* tbuf    = (__half*)alloc((size_t)N_NODES * 128 * 2);  // fp16 t rows
    __half* hbuf    = (__half*)alloc((size_t)N_NODES * 128 * 2);  // fp16 activations
    // bucket planar arrays alias hbuf (12.8MB < 25.6MB; dead before gemm1 output use)
    int*    bktRow  = (int*)hbuf;
    int*    bktCol  = bktRow + N_EDGES;
    (void)ws_size; (void)in_sizes; (void)n_in; (void)out_size;

    int ptiles = (N_EDGES + PTILE - 1) / PTILE;   // 391

    // --- preprocessing: no random global atomics ---
    detect_i64<<<1, 256, 0, stream>>>((const int*)ei, flag);
    init_pre<<<1, 256, 0, stream>>>(bsize);
    hist_buckets<<<ptiles, 256, 0, stream>>>(ei, flag, bsize);
    scan_buckets<<<1, 256, 0, stream>>>(bsize, bbase, bcur);
    partition_edges<<<ptiles, 256, 0, stream>>>(ei, flag, bcur, bktRow, bktCol);
    bucket_stats<<<NB, 512, 0, stream>>>(bktRow, bbase, deg, rowst);
    compute_dis<<<(N_NODES + 255) / 256, 256, 0, stream>>>(deg, dis);
    scatter_bucket<<<NB, 512, 0, stream>>>(bktRow, bktCol, bbase, rowst, dis, csr_cn);

    int gblocks = (N_NODES + 63) / 64;   // 1563

    // --- layer 1 (fp32 in) ---
    gemm_mfma<float, 8><<<gblocks, 256, 0, stream>>>(x, W1, tbuf, 128);
    agg_c128<<<(N_NODES + 3) / 4, 256, 0, stream>>>(tbuf, rowst, deg, csr_cn, dis, b1, hbuf, 1);
    // --- layer 2 (fp16 in) ---
    gemm_mfma<_Float16, 8><<<gblocks, 256, 0, stream>>>((_Float16*)hbuf, W2, tbuf, 128);
    agg_c128<<<(N_NODES + 3) / 4, 256, 0, stream>>>(tbuf, rowst, deg, csr_cn, dis, b2, hbuf, 1);
    // --- layer 3 (fp16 in, 47 cols) ---
    gemm_mfma<_Float16, 3><<<gblocks, 256, 0, stream>>>((_Float16*)hbuf, W3, tbuf, 47);
    agg_c47<<<(N_NODES + 3) / 4, 256, 0, stream>>>(tbuf, rowst, deg, csr_cn, dis, b3, out);
}